// Round 4
// baseline (499.179 us; speedup 1.0000x reference)
//
#include <hip/hip_runtime.h>
#include <hip/hip_bf16.h>

typedef unsigned short ushort_t;
typedef __attribute__((ext_vector_type(8))) short v8s;   // 8 bf16 = 4 VGPR (MFMA A/B)
typedef __attribute__((ext_vector_type(4))) float v4f;   // MFMA C/D

// ---------------------------------------------------------------------------
// ws layout (ushort indices unless noted):
//   pack1 [0, 22528)        conv1 A-frags (weights), dense K: [ks 11][nt 4][lane 64][8]
//   pack2 [22528, 26624)    conv2 A-frags hi|lo-in-j: [nt 4][mt2 2][lane 64][8]
//   pack3 [26624, 47104)    conv3 B-frags (hi only): [ks 40][lane 64][8]
//   floats at us 47104 (float idx 23552):
#define B1F_F   23552      // 64
#define B2F_F   23616      // 32
#define B3F_F   23648      // 4
#define WTAB_F  23652      // 32 (8 phases x 4 taps)
#define FLAG_I  23684      // int (1 = bf16 inputs/outputs, 0 = fp32)
#define PK1_US  0
#define PK2_US  22528
#define PK3_US  26624
#define UP_US   48256      // bf16 NHWC [16][256][256][4]  (4M us = 8 MB)
#define H2_US   4242560    // bf16 NHWC [16][256][256][32] (32M us = 64 MB)
#define CVT_TOTAL (47104 + 132)
// ---------------------------------------------------------------------------

__device__ __forceinline__ ushort_t f2us(float v) {
  __hip_bfloat16 h = __float2bfloat16(v);
  return *reinterpret_cast<ushort_t*>(&h);
}
__device__ __forceinline__ float us2f(unsigned int u) { return __uint_as_float(u << 16); }

// RNE-pack two finite floats into two bf16 (lo = a, hi = b). Bit-exact RNE.
__device__ __forceinline__ unsigned int bfpair(float a, float b) {
  unsigned int ua = __float_as_uint(a), ub = __float_as_uint(b);
  ua += 0x7fffu + ((ua >> 16) & 1u);
  ub += 0x7fffu + ((ub >> 16) & 1u);
  return (ua >> 16) | (ub & 0xffff0000u);
}

// HW packed f32->bf16 (RNE under default MODE.round) — 1 VALU op vs ~7 for bfpair.
__device__ __forceinline__ unsigned int cvtpk(float a, float b) {
  unsigned int r;
  asm("v_cvt_pk_bf16_f32 %0, %1, %2" : "=v"(r) : "v"(a), "v"(b));
  return r;
}

// direct global -> LDS DMA, 16 B per lane (dest must be linear in lane order)
__device__ __forceinline__ void gload_lds16(const void* g, void* l) {
  __builtin_amdgcn_global_load_lds(
      (const __attribute__((address_space(1))) void*)g,
      (__attribute__((address_space(3))) void*)l, 16, 0, 0);
}

__device__ __forceinline__ float load_in(const void* p, int i, int isbf16) {
  if (isbf16) return us2f(((const unsigned short*)p)[i]);
  return ((const float*)p)[i];
}
__device__ __forceinline__ float4 load_in4(const void* p, int i4, int isbf16) {
  if (isbf16) {
    unsigned long long q = *(const unsigned long long*)((const unsigned short*)p + i4);
    return make_float4(us2f((unsigned int)(q & 0xffff)),
                       us2f((unsigned int)((q >> 16) & 0xffff)),
                       us2f((unsigned int)((q >> 32) & 0xffff)),
                       us2f((unsigned int)((q >> 48) & 0xffff)));
  }
  return *(const float4*)((const float*)p + i4);
}

__device__ __forceinline__ float cubicw(float d) {
  const float Ac = -0.75f;
  d = fabsf(d);
  float d2 = d * d, d3 = d2 * d;
  if (d <= 1.f) return (Ac + 2.f) * d3 - (Ac + 3.f) * d2 + 1.f;
  if (d < 2.f)  return Ac * d3 - 5.f * Ac * d2 + 8.f * Ac * d - 4.f * Ac;
  return 0.f;
}

// ---------------- K_cvt: inline dtype probe + build weight packs -----------
__global__ __launch_bounds__(256) void k_cvt(
    const void* __restrict__ x,
    const void* __restrict__ w1, const void* __restrict__ b1,
    const void* __restrict__ w2, const void* __restrict__ b2,
    const void* __restrict__ w3, const void* __restrict__ b3,
    ushort_t* __restrict__ wsus, float* __restrict__ wsf,
    int* __restrict__ flag) {
  __shared__ int scnt;
  const int tid = threadIdx.x;
  if (tid == 0) scnt = 0;
  __syncthreads();
  {
    const unsigned short* xr = (const unsigned short*)x;
    int c = 0;
    for (int s = tid; s < 512; s += 256) {
      unsigned short h = xr[2 * s];
      int e = (h >> 7) & 0xFF;
      if (e >= 110 && e <= 135) c++;
    }
    if (c) atomicAdd(&scnt, c);
  }
  __syncthreads();
  const int f = (scnt >= 256) ? 1 : 0;
  if (blockIdx.x == 0 && tid == 0) flag[0] = f;

  int i = blockIdx.x * 256 + tid;
  if (i >= CVT_TOTAL) return;
  if (i < 22528) {
    // pack1 dense: k = ks*32+quad*8+j; k<324: tap=k>>2 (ky=tap/9,kx=tap%9), ic=k&3
    int j  = i & 7;
    int l  = (i >> 3) & 63;
    int nt = (i >> 9) & 3;
    int ks = i >> 11;
    int k  = ks * 32 + ((l >> 4) & 3) * 8 + j;
    int oc = nt * 16 + (l & 15);
    float v = 0.f;
    if (k < 324) {
      int tap = k >> 2, ic = k & 3;
      int ky = tap / 9, kx = tap - ky * 9;
      v = load_in(w1, ((oc * 4 + ic) * 9 + ky) * 9 + kx, f);
    }
    wsus[PK1_US + i] = f2us(v);
    return;
  }
  if (i < 26624) {
    // pack2: [nt][mt2][lane][8]; j<4 = hi(w2), j>=4 = lo residual
    int t = i - 22528;
    int j   = t & 7;
    int l   = (t >> 3) & 63;
    int mt2 = (t >> 9) & 1;
    int nt  = (t >> 10) & 3;
    int oc1 = nt * 16 + ((l >> 4) & 3) * 4 + (j & 3);
    int oc2 = mt2 * 16 + (l & 15);
    float w = load_in(w2, oc2 * 64 + oc1, f);
    float hi = us2f(f2us(w));
    wsus[PK2_US + t] = (j < 4) ? f2us(w) : f2us(w - hi);
    return;
  }
  if (i < 47104) {
    // pack3 (hi only): [ks 40][lane][8]; k=ky*256+jj*32+ic; n=dx*4+oc
    int t = i - 26624;
    int j8 = t & 7;
    int l  = (t >> 3) & 63;
    int ks = t >> 9;
    int k  = ks * 32 + ((l >> 4) & 3) * 8 + j8;
    int n  = l & 15;
    int ky = k >> 8, jj = (k >> 5) & 7, ic = k & 31;
    int dx = n >> 2, oc = n & 3;
    int kx = jj - dx;
    float w = 0.f;
    if (kx >= 0 && kx <= 4)
      w = load_in(w3, ((oc * 32 + ic) * 5 + ky) * 5 + kx, f);
    wsus[PK3_US + t] = f2us(w);
    return;
  }
  int t = i - 47104;
  if (t < 64) { wsf[B1F_F + t] = load_in(b1, t, f); return; }
  if (t < 96) { wsf[B2F_F + (t - 64)] = load_in(b2, t - 64, f); return; }
  if (t < 100) { wsf[B3F_F + (t - 96)] = load_in(b3, t - 96, f); return; }
  if (t < 132) {
    int p = (t - 100) >> 2, a = (t - 100) & 3;
    float frac = (p + 0.5f) * 0.125f - 0.5f;
    float fl = floorf(frac);
    float tt = frac - fl;
    wsf[WTAB_F + (t - 100)] = cubicw(tt - (float)(a - 1));
  }
}

// ---------------- K1: bicubic x8 upscale -> bf16 NHWC ----------------------
__global__ __launch_bounds__(256) void k_upscale(
    const void* __restrict__ x, ushort_t* __restrict__ up,
    const float* __restrict__ wsf, const int* __restrict__ flag) {
  const int f = flag[0];
  int n = blockIdx.x * 256 + threadIdx.x;
  int xo = n & 255, yo = (n >> 8) & 255, b = n >> 16;
  int px = xo & 7, py = yo & 7;
  const float* wt = wsf + WTAB_F;
  float4 wx = *(const float4*)(wt + px * 4);
  float4 wy = *(const float4*)(wt + py * 4);
  float wya[4] = {wy.x, wy.y, wy.z, wy.w};
  int bx = (xo >> 3) + ((px >= 4) ? 0 : -1);
  int by = (yo >> 3) + ((py >= 4) ? 0 : -1);
  int ix0 = min(max(bx - 1, 0), 31), ix1 = min(max(bx, 0), 31);
  int ix2 = min(max(bx + 1, 0), 31), ix3 = min(max(bx + 2, 0), 31);
  float ax = 0.f, ay = 0.f, az = 0.f, aw = 0.f;
#pragma unroll
  for (int a = 0; a < 4; a++) {
    int iy = min(max(by + a - 1, 0), 31);
    int rowb = (b * 32 + iy) * 32;
    float4 p0 = load_in4(x, (rowb + ix0) * 4, f);
    float4 p1 = load_in4(x, (rowb + ix1) * 4, f);
    float4 p2 = load_in4(x, (rowb + ix2) * 4, f);
    float4 p3 = load_in4(x, (rowb + ix3) * 4, f);
    float rx = wx.x * p0.x + wx.y * p1.x + wx.z * p2.x + wx.w * p3.x;
    float ry = wx.x * p0.y + wx.y * p1.y + wx.z * p2.y + wx.w * p3.y;
    float rz = wx.x * p0.z + wx.y * p1.z + wx.z * p2.z + wx.w * p3.z;
    float rw = wx.x * p0.w + wx.y * p1.w + wx.z * p2.w + wx.w * p3.w;
    ax = fmaf(wya[a], rx, ax); ay = fmaf(wya[a], ry, ay);
    az = fmaf(wya[a], rz, az); aw = fmaf(wya[a], rw, aw);
  }
  unsigned long long q =
      (unsigned long long)bfpair(ax, ay) |
      ((unsigned long long)bfpair(az, aw) << 32);
  *(unsigned long long*)(up + n * 4) = q;
}

// ---------------- K2: MFMA conv9x9(4->64)+ReLU -> MFMA conv1x1(64->32)+ReLU
// r2 dispatch-per-tile structure (proven: clean 64MB write, FETCH 8MB) with a
// 32x32-px block tile: 512 thr = 8 waves, each wave owns 8 mtiles x 4 nt.
// A-frag LDS reads now feed 32 MFMAs each (was 16): per-1024px LDS-port
// cycles drop ~25% below MFMA cycles -> K-loop flips to MFMA-bound.
// pack1 staged once per 1024 px; patch halo 1.56x (was 1.875x).
__global__ __launch_bounds__(512, 4) void k_conv12(
    const ushort_t* __restrict__ up, const ushort_t* __restrict__ wsus,
    const float* __restrict__ wsf, ushort_t* __restrict__ h2) {
  __shared__ __align__(16) ushort_t patchA[40 * 40 * 4];  // 12800 B
  __shared__ __align__(16) ushort_t pack1L[22528];        // 45056 B
  const int b  = blockIdx.z;
  const int x0 = blockIdx.x * 32, y0 = blockIdx.y * 32;
  const int tid = threadIdx.x;

  // stage pack1 -> LDS via direct DMA (2816 x 16B; dest linear in lane order)
  {
    const ushort_t* src = wsus + PK1_US;
#pragma unroll
    for (int i = 0; i < 6; ++i) {
      int e = tid + i * 512;
      if (e < 2816)                              // wave-uniform guard
        gload_lds16(src + e * 8, pack1L + e * 8);
    }
  }
  // stage 40x40 patch positions from bf16 NHWC up (zero pad)
#pragma unroll
  for (int i = 0; i < 4; ++i) {
    int e = tid + i * 512;                  // need 1600
    if (e < 1600) {                         // wave-uniform (64 = 1 wave tail)
      int yy = e / 40, xx = e - yy * 40;
      int gy = y0 + yy - 4, gx = x0 + xx - 4;
      unsigned long long q = 0ull;
      if (gy >= 0 && gy < 256 && gx >= 0 && gx < 256)
        q = *(const unsigned long long*)(up + (((b * 256 + gy) * 256 + gx) << 2));
      *(unsigned long long*)(patchA + e * 4) = q;
    }
  }
  __syncthreads();

  const int lane = tid & 63, wave = tid >> 6;
  const int quad = lane >> 4, lc = lane & 15;
  int base_m[8], pix0_[8];
#pragma unroll
  for (int i = 0; i < 8; ++i) {
    int mt = wave * 8 + i;                   // 0..63
    int py = mt >> 1, pxh = (mt & 1) << 4;   // py 0..31, pxh 0/16
    base_m[i] = (py * 40 + pxh + lc) << 2;   // ushort idx of (py, pxh+lc, ic0)
    pix0_[i] = py * 32 + pxh;
  }

  // bias b1 -> accumulator init (C-in of the first MFMA)
  float4 b1q[4];
#pragma unroll
  for (int nt = 0; nt < 4; ++nt)
    b1q[nt] = *(const float4*)(wsf + B1F_F + nt * 16 + quad * 4);
  v4f acc[8][4];
#pragma unroll
  for (int i = 0; i < 8; ++i)
#pragma unroll
    for (int nt = 0; nt < 4; ++nt)
      acc[i][nt] = (v4f){b1q[nt].x, b1q[nt].y, b1q[nt].z, b1q[nt].w};

  const v8s* __restrict__ Ap1 = (const v8s*)pack1L;
#pragma unroll
  for (int ks = 0; ks < 11; ++ks) {
    v8s Af[4];
#pragma unroll
    for (int nt = 0; nt < 4; ++nt) Af[nt] = Ap1[(ks * 4 + nt) * 64 + lane];
    int tap0 = ks * 8 + quad * 2;
    int tap1 = min(tap0 + 1, 80);
    tap0 = min(tap0, 80);
    int ky0 = tap0 / 9, kx0 = tap0 - ky0 * 9;
    int ky1 = tap1 / 9, kx1 = tap1 - ky1 * 9;
    int off0 = (ky0 * 40 + kx0) << 2;
    int off1 = (ky1 * 40 + kx1) << 2;
#pragma unroll
    for (int i = 0; i < 8; ++i) {
      union { unsigned long long q[2]; v8s v; } u;
      u.q[0] = *(const unsigned long long*)(patchA + base_m[i] + off0);
      u.q[1] = *(const unsigned long long*)(patchA + base_m[i] + off1);
#pragma unroll
      for (int nt = 0; nt < 4; ++nt)
        acc[i][nt] = __builtin_amdgcn_mfma_f32_16x16x32_bf16(Af[nt], u.v, acc[i][nt], 0, 0, 0);
    }
  }

  // epilogue: ReLU, pack -> conv2 MFMA (b2 folded into C-init) -> ReLU, store
  v8s w2f[4][2];
#pragma unroll
  for (int nt = 0; nt < 4; ++nt)
#pragma unroll
    for (int mt2 = 0; mt2 < 2; ++mt2)
      w2f[nt][mt2] = ((const v8s*)(wsus + PK2_US))[(nt * 2 + mt2) * 64 + lane];
  float4 b2q[2];
#pragma unroll
  for (int mt2 = 0; mt2 < 2; ++mt2)
    b2q[mt2] = *(const float4*)(wsf + B2F_F + mt2 * 16 + quad * 4);

#pragma unroll
  for (int i = 0; i < 8; ++i) {
    v4f a2[2];
    a2[0] = (v4f){b2q[0].x, b2q[0].y, b2q[0].z, b2q[0].w};
    a2[1] = (v4f){b2q[1].x, b2q[1].y, b2q[1].z, b2q[1].w};
#pragma unroll
    for (int nt = 0; nt < 4; ++nt) {
      float r0 = fmaxf(acc[i][nt][0], 0.f);
      float r1 = fmaxf(acc[i][nt][1], 0.f);
      float r2 = fmaxf(acc[i][nt][2], 0.f);
      float r3 = fmaxf(acc[i][nt][3], 0.f);
      unsigned int u0 = cvtpk(r0, r1), u1 = cvtpk(r2, r3);
      union { unsigned int q[4]; v8s v; } bu;
      bu.q[0] = u0; bu.q[1] = u1; bu.q[2] = u0; bu.q[3] = u1;
#pragma unroll
      for (int mt2 = 0; mt2 < 2; ++mt2)
        a2[mt2] = __builtin_amdgcn_mfma_f32_16x16x32_bf16(w2f[nt][mt2], bu.v, a2[mt2], 0, 0, 0);
    }
    int pix = pix0_[i] + lc;
    int gy = y0 + (pix >> 5), gx = x0 + (pix & 31);
    ushort_t* dst = h2 + (((b * 256 + gy) * 256 + gx) << 5) + (quad << 2);
#pragma unroll
    for (int mt2 = 0; mt2 < 2; ++mt2) {
      float v0 = fmaxf(a2[mt2][0], 0.f);
      float v1 = fmaxf(a2[mt2][1], 0.f);
      float v2 = fmaxf(a2[mt2][2], 0.f);
      float v3 = fmaxf(a2[mt2][3], 0.f);
      unsigned long long q =
          (unsigned long long)cvtpk(v0, v1) |
          ((unsigned long long)cvtpk(v2, v3) << 32);
      *(unsigned long long*)(dst + mt2 * 16) = q;
    }
  }
}

// ---------------- K3: MFMA conv5x5(32->4) via dx-in-N trick ----------------
// 16x16 tile: patch = 25.9 KB -> 6 blocks/CU LDS-wise.  B-frags streamed from
// L2 per ks (coalesced, L2-hot) instead of 128 pinned VGPRs;
// launch_bounds(256,5) -> ~5 resident blocks/CU to overlap staging latency.
__global__ __launch_bounds__(256, 5) void k_conv3(
    const ushort_t* __restrict__ h2, const ushort_t* __restrict__ wsus,
    const float* __restrict__ wsf, void* __restrict__ out,
    const int* __restrict__ flag) {
  __shared__ __align__(16) ushort_t patch[20 * 648];  // [y 20][x 20][ic 32] + 8 pad/row
  const int b  = blockIdx.z;
  const int x0 = blockIdx.x * 16, y0 = blockIdx.y * 16;
  const int tid = threadIdx.x;

  for (int e = tid; e < 400; e += 256) {
    int yy = e / 20, xx = e - yy * 20;
    int gy = y0 + yy - 2, gx = x0 + xx - 2;
    ushort_t* dst = patch + yy * 648 + xx * 32;
    if (gy >= 0 && gy < 256 && gx >= 0 && gx < 256) {
      const ushort_t* src = h2 + (((b * 256 + gy) * 256 + gx) << 5);
#pragma unroll
      for (int c = 0; c < 4; ++c)
        *(float4*)(dst + c * 8) = *(const float4*)(src + c * 8);
    } else {
      float4 z = make_float4(0.f, 0.f, 0.f, 0.f);
#pragma unroll
      for (int c = 0; c < 4; ++c) *(float4*)(dst + c * 8) = z;
    }
  }

  const int lane = tid & 63, wave = tid >> 6;
  const int quad = lane >> 4, lc = lane & 15;
  __syncthreads();

  // bias b3 folded into accumulator init
  float b3v = (wsf + B3F_F)[lc & 3];
  v4f acc = (v4f){b3v, b3v, b3v, b3v};

  const v8s* __restrict__ Bp3 = (const v8s*)(wsus + PK3_US);
#pragma unroll
  for (int ks = 0; ks < 40; ++ks) {
    int ky = ks >> 3, j = ks & 7;
    int rowoff = (lc + ky) * 648 + j * 32 + quad * 8;
    v8s Bf = Bp3[ks * 64 + lane];                       // L2-hot, coalesced
    v8s Af = *(const v8s*)(patch + rowoff + wave * 128);
    acc = __builtin_amdgcn_mfma_f32_16x16x32_bf16(Af, Bf, acc, 0, 0, 0);
  }

  // epilogue: C/D row=quad*4+r -> y_local, col=lc -> (dx=lc>>2, oc=lc&3)
  const int fl = flag[0];
#pragma unroll
  for (int r = 0; r < 4; ++r) {
    int gy = y0 + (quad << 2) + r;
    int gx = x0 + (wave << 2) + (lc >> 2);
    int idx = (((b * 256 + gy) * 256 + gx) << 2) + (lc & 3);
    float vv = acc[r];
    if (fl) ((ushort_t*)out)[idx] = f2us(vv);
    else    ((float*)out)[idx] = vv;
  }
}

// ---------------------------------------------------------------------------
extern "C" void kernel_launch(void* const* d_in, const int* in_sizes, int n_in,
                              void* d_out, int out_size, void* d_ws, size_t ws_size,
                              hipStream_t stream) {
  const void* x  = d_in[0];
  const void* w1 = d_in[1];
  const void* b1 = d_in[2];
  const void* w2 = d_in[3];
  const void* b2 = d_in[4];
  const void* w3 = d_in[5];
  const void* b3 = d_in[6];

  ushort_t* wsus = (ushort_t*)d_ws;
  float* wsf = (float*)d_ws;
  int* flag = (int*)((float*)d_ws + FLAG_I);
  ushort_t* up = wsus + UP_US;
  ushort_t* h2 = wsus + H2_US;

  k_cvt<<<(CVT_TOTAL + 255) / 256, 256, 0, stream>>>(x, w1, b1, w2, b2, w3, b3,
                                                     wsus, wsf, flag);
  k_upscale<<<4096, 256, 0, stream>>>(x, up, wsf, flag);
  k_conv12<<<dim3(8, 8, 16), 512, 0, stream>>>(up, wsus, wsf, h2);
  k_conv3<<<dim3(16, 16, 16), 256, 0, stream>>>(h2, wsus, wsf, d_out, flag);
}

// Round 5
// 161.430 us; speedup vs baseline: 3.0922x; 3.0922x over previous
//
#include <hip/hip_runtime.h>
#include <hip/hip_bf16.h>

typedef unsigned short ushort_t;
typedef __attribute__((ext_vector_type(8))) short v8s;   // 8 bf16 = 4 VGPR (MFMA A/B)
typedef __attribute__((ext_vector_type(4))) float v4f;   // MFMA C/D

// ---------------------------------------------------------------------------
// ws layout (ushort indices unless noted):
//   pack1 [0, 22528)        conv1 A-frags (weights), dense K: [ks 11][nt 4][lane 64][8]
//   pack2 [22528, 26624)    conv2 A-frags hi|lo-in-j: [nt 4][mt2 2][lane 64][8]
//   pack3 [26624, 47104)    conv3 B-frags (hi only): [ks 40][lane 64][8]
//   floats at us 47104 (float idx 23552):
#define B1F_F   23552      // 64
#define B2F_F   23616      // 32
#define B3F_F   23648      // 4
#define WTAB_F  23652      // 32 (8 phases x 4 taps)
#define FLAG_I  23684      // int (1 = bf16 inputs/outputs, 0 = fp32)
#define PK1_US  0
#define PK2_US  22528
#define PK3_US  26624
#define UP_US   48256      // bf16 NHWC [16][256][256][4]  (4M us = 8 MB)
#define H2_US   4242560    // bf16 NHWC [16][256][256][32] (32M us = 64 MB)
#define CVT_TOTAL (47104 + 132)
// ---------------------------------------------------------------------------

__device__ __forceinline__ ushort_t f2us(float v) {
  __hip_bfloat16 h = __float2bfloat16(v);
  return *reinterpret_cast<ushort_t*>(&h);
}
__device__ __forceinline__ float us2f(unsigned int u) { return __uint_as_float(u << 16); }

// RNE-pack two finite floats into two bf16 (lo = a, hi = b). Bit-exact RNE.
__device__ __forceinline__ unsigned int bfpair(float a, float b) {
  unsigned int ua = __float_as_uint(a), ub = __float_as_uint(b);
  ua += 0x7fffu + ((ua >> 16) & 1u);
  ub += 0x7fffu + ((ub >> 16) & 1u);
  return (ua >> 16) | (ub & 0xffff0000u);
}

// HW packed f32->bf16 (RNE under default MODE.round) — 1 VALU op vs ~7 for bfpair.
__device__ __forceinline__ unsigned int cvtpk(float a, float b) {
  unsigned int r;
  asm("v_cvt_pk_bf16_f32 %0, %1, %2" : "=v"(r) : "v"(a), "v"(b));
  return r;
}

// direct global -> LDS DMA, 16 B per lane (dest must be linear in lane order)
__device__ __forceinline__ void gload_lds16(const void* g, void* l) {
  __builtin_amdgcn_global_load_lds(
      (const __attribute__((address_space(1))) void*)g,
      (__attribute__((address_space(3))) void*)l, 16, 0, 0);
}

__device__ __forceinline__ float load_in(const void* p, int i, int isbf16) {
  if (isbf16) return us2f(((const unsigned short*)p)[i]);
  return ((const float*)p)[i];
}
__device__ __forceinline__ float4 load_in4(const void* p, int i4, int isbf16) {
  if (isbf16) {
    unsigned long long q = *(const unsigned long long*)((const unsigned short*)p + i4);
    return make_float4(us2f((unsigned int)(q & 0xffff)),
                       us2f((unsigned int)((q >> 16) & 0xffff)),
                       us2f((unsigned int)((q >> 32) & 0xffff)),
                       us2f((unsigned int)((q >> 48) & 0xffff)));
  }
  return *(const float4*)((const float*)p + i4);
}

__device__ __forceinline__ float cubicw(float d) {
  const float Ac = -0.75f;
  d = fabsf(d);
  float d2 = d * d, d3 = d2 * d;
  if (d <= 1.f) return (Ac + 2.f) * d3 - (Ac + 3.f) * d2 + 1.f;
  if (d < 2.f)  return Ac * d3 - 5.f * Ac * d2 + 8.f * Ac * d - 4.f * Ac;
  return 0.f;
}

// ---------------- K_cvt: inline dtype probe + build weight packs -----------
__global__ __launch_bounds__(256) void k_cvt(
    const void* __restrict__ x,
    const void* __restrict__ w1, const void* __restrict__ b1,
    const void* __restrict__ w2, const void* __restrict__ b2,
    const void* __restrict__ w3, const void* __restrict__ b3,
    ushort_t* __restrict__ wsus, float* __restrict__ wsf,
    int* __restrict__ flag) {
  __shared__ int scnt;
  const int tid = threadIdx.x;
  if (tid == 0) scnt = 0;
  __syncthreads();
  {
    const unsigned short* xr = (const unsigned short*)x;
    int c = 0;
    for (int s = tid; s < 512; s += 256) {
      unsigned short h = xr[2 * s];
      int e = (h >> 7) & 0xFF;
      if (e >= 110 && e <= 135) c++;
    }
    if (c) atomicAdd(&scnt, c);
  }
  __syncthreads();
  const int f = (scnt >= 256) ? 1 : 0;
  if (blockIdx.x == 0 && tid == 0) flag[0] = f;

  int i = blockIdx.x * 256 + tid;
  if (i >= CVT_TOTAL) return;
  if (i < 22528) {
    // pack1 dense: k = ks*32+quad*8+j; k<324: tap=k>>2 (ky=tap/9,kx=tap%9), ic=k&3
    int j  = i & 7;
    int l  = (i >> 3) & 63;
    int nt = (i >> 9) & 3;
    int ks = i >> 11;
    int k  = ks * 32 + ((l >> 4) & 3) * 8 + j;
    int oc = nt * 16 + (l & 15);
    float v = 0.f;
    if (k < 324) {
      int tap = k >> 2, ic = k & 3;
      int ky = tap / 9, kx = tap - ky * 9;
      v = load_in(w1, ((oc * 4 + ic) * 9 + ky) * 9 + kx, f);
    }
    wsus[PK1_US + i] = f2us(v);
    return;
  }
  if (i < 26624) {
    // pack2: [nt][mt2][lane][8]; j<4 = hi(w2), j>=4 = lo residual
    int t = i - 22528;
    int j   = t & 7;
    int l   = (t >> 3) & 63;
    int mt2 = (t >> 9) & 1;
    int nt  = (t >> 10) & 3;
    int oc1 = nt * 16 + ((l >> 4) & 3) * 4 + (j & 3);
    int oc2 = mt2 * 16 + (l & 15);
    float w = load_in(w2, oc2 * 64 + oc1, f);
    float hi = us2f(f2us(w));
    wsus[PK2_US + t] = (j < 4) ? f2us(w) : f2us(w - hi);
    return;
  }
  if (i < 47104) {
    // pack3 (hi only): [ks 40][lane][8]; k=ky*256+jj*32+ic; n=dx*4+oc
    int t = i - 26624;
    int j8 = t & 7;
    int l  = (t >> 3) & 63;
    int ks = t >> 9;
    int k  = ks * 32 + ((l >> 4) & 3) * 8 + j8;
    int n  = l & 15;
    int ky = k >> 8, jj = (k >> 5) & 7, ic = k & 31;
    int dx = n >> 2, oc = n & 3;
    int kx = jj - dx;
    float w = 0.f;
    if (kx >= 0 && kx <= 4)
      w = load_in(w3, ((oc * 32 + ic) * 5 + ky) * 5 + kx, f);
    wsus[PK3_US + t] = f2us(w);
    return;
  }
  int t = i - 47104;
  if (t < 64) { wsf[B1F_F + t] = load_in(b1, t, f); return; }
  if (t < 96) { wsf[B2F_F + (t - 64)] = load_in(b2, t - 64, f); return; }
  if (t < 100) { wsf[B3F_F + (t - 96)] = load_in(b3, t - 96, f); return; }
  if (t < 132) {
    int p = (t - 100) >> 2, a = (t - 100) & 3;
    float frac = (p + 0.5f) * 0.125f - 0.5f;
    float fl = floorf(frac);
    float tt = frac - fl;
    wsf[WTAB_F + (t - 100)] = cubicw(tt - (float)(a - 1));
  }
}

// ---------------- K1: bicubic x8 upscale -> bf16 NHWC ----------------------
__global__ __launch_bounds__(256) void k_upscale(
    const void* __restrict__ x, ushort_t* __restrict__ up,
    const float* __restrict__ wsf, const int* __restrict__ flag) {
  const int f = flag[0];
  int n = blockIdx.x * 256 + threadIdx.x;
  int xo = n & 255, yo = (n >> 8) & 255, b = n >> 16;
  int px = xo & 7, py = yo & 7;
  const float* wt = wsf + WTAB_F;
  float4 wx = *(const float4*)(wt + px * 4);
  float4 wy = *(const float4*)(wt + py * 4);
  float wya[4] = {wy.x, wy.y, wy.z, wy.w};
  int bx = (xo >> 3) + ((px >= 4) ? 0 : -1);
  int by = (yo >> 3) + ((py >= 4) ? 0 : -1);
  int ix0 = min(max(bx - 1, 0), 31), ix1 = min(max(bx, 0), 31);
  int ix2 = min(max(bx + 1, 0), 31), ix3 = min(max(bx + 2, 0), 31);
  float ax = 0.f, ay = 0.f, az = 0.f, aw = 0.f;
#pragma unroll
  for (int a = 0; a < 4; a++) {
    int iy = min(max(by + a - 1, 0), 31);
    int rowb = (b * 32 + iy) * 32;
    float4 p0 = load_in4(x, (rowb + ix0) * 4, f);
    float4 p1 = load_in4(x, (rowb + ix1) * 4, f);
    float4 p2 = load_in4(x, (rowb + ix2) * 4, f);
    float4 p3 = load_in4(x, (rowb + ix3) * 4, f);
    float rx = wx.x * p0.x + wx.y * p1.x + wx.z * p2.x + wx.w * p3.x;
    float ry = wx.x * p0.y + wx.y * p1.y + wx.z * p2.y + wx.w * p3.y;
    float rz = wx.x * p0.z + wx.y * p1.z + wx.z * p2.z + wx.w * p3.z;
    float rw = wx.x * p0.w + wx.y * p1.w + wx.z * p2.w + wx.w * p3.w;
    ax = fmaf(wya[a], rx, ax); ay = fmaf(wya[a], ry, ay);
    az = fmaf(wya[a], rz, az); aw = fmaf(wya[a], rw, aw);
  }
  unsigned long long q =
      (unsigned long long)bfpair(ax, ay) |
      ((unsigned long long)bfpair(az, aw) << 32);
  *(unsigned long long*)(up + n * 4) = q;
}

// ---------------- K2: MFMA conv9x9(4->64)+ReLU -> MFMA conv1x1(64->32)+ReLU
// 512 thr = 8 waves; block tile 32x16 px (r2-proven config: 49.4us, FETCH
// 7.9MB, WRITE 64MB clean).  ONE pack1 LDS copy feeds 8 waves, 2 blocks/CU.
// NOTE (r4 lesson): acc[4][4]=64 acc regs + ~64 VGPR fits the 128-reg budget
// of __launch_bounds__(512,4); acc[8][4] does NOT (spills -> 2GB scratch).
__global__ __launch_bounds__(512, 4) void k_conv12(
    const ushort_t* __restrict__ up, const ushort_t* __restrict__ wsus,
    const float* __restrict__ wsf, ushort_t* __restrict__ h2) {
  __shared__ __align__(16) ushort_t patchA[24 * 40 * 4];  // 7680 B
  __shared__ __align__(16) ushort_t pack1L[22528];        // 45056 B
  const int b  = blockIdx.z;
  const int x0 = blockIdx.x * 32, y0 = blockIdx.y * 16;
  const int tid = threadIdx.x;

  // stage pack1 -> LDS via direct DMA (2816 x 16B; dest linear in lane order)
  {
    const ushort_t* src = wsus + PK1_US;
#pragma unroll
    for (int i = 0; i < 6; ++i) {
      int e = tid + i * 512;
      if (e < 2816)                              // wave-uniform guard
        gload_lds16(src + e * 8, pack1L + e * 8);
    }
  }
  // stage 24x40 patch positions from bf16 NHWC up (zero pad)
#pragma unroll
  for (int i = 0; i < 2; ++i) {
    int e = tid + i * 512;                  // 0..1023, need 960
    if (e < 960) {                          // wave-uniform (448 = 7 waves)
      int yy = e / 40, xx = e - yy * 40;
      int gy = y0 + yy - 4, gx = x0 + xx - 4;
      unsigned long long q = 0ull;
      if (gy >= 0 && gy < 256 && gx >= 0 && gx < 256)
        q = *(const unsigned long long*)(up + (((b * 256 + gy) * 256 + gx) << 2));
      *(unsigned long long*)(patchA + e * 4) = q;
    }
  }
  __syncthreads();

  const int lane = tid & 63, wave = tid >> 6;
  const int quad = lane >> 4, lc = lane & 15;
  int base_m[4], pix0_[4];
#pragma unroll
  for (int i = 0; i < 4; ++i) {
    int mt = wave * 4 + i;                   // 0..31
    int py = mt >> 1, pxh = (mt & 1) << 4;   // py 0..15, pxh 0/16
    base_m[i] = (py * 40 + pxh + lc) << 2;   // ushort idx of (py, pxh+lc, ic0)
    pix0_[i] = py * 32 + pxh;
  }

  // bias b1 -> accumulator init (C-in of the first MFMA)
  float4 b1q[4];
#pragma unroll
  for (int nt = 0; nt < 4; ++nt)
    b1q[nt] = *(const float4*)(wsf + B1F_F + nt * 16 + quad * 4);
  v4f acc[4][4];
#pragma unroll
  for (int i = 0; i < 4; ++i)
#pragma unroll
    for (int nt = 0; nt < 4; ++nt)
      acc[i][nt] = (v4f){b1q[nt].x, b1q[nt].y, b1q[nt].z, b1q[nt].w};

  const v8s* __restrict__ Ap1 = (const v8s*)pack1L;
#pragma unroll
  for (int ks = 0; ks < 11; ++ks) {
    v8s Af[4];
#pragma unroll
    for (int nt = 0; nt < 4; ++nt) Af[nt] = Ap1[(ks * 4 + nt) * 64 + lane];
    int tap0 = ks * 8 + quad * 2;
    int tap1 = min(tap0 + 1, 80);
    tap0 = min(tap0, 80);
    int ky0 = tap0 / 9, kx0 = tap0 - ky0 * 9;
    int ky1 = tap1 / 9, kx1 = tap1 - ky1 * 9;
    int off0 = (ky0 * 40 + kx0) << 2;
    int off1 = (ky1 * 40 + kx1) << 2;
#pragma unroll
    for (int i = 0; i < 4; ++i) {
      union { unsigned long long q[2]; v8s v; } u;
      u.q[0] = *(const unsigned long long*)(patchA + base_m[i] + off0);
      u.q[1] = *(const unsigned long long*)(patchA + base_m[i] + off1);
#pragma unroll
      for (int nt = 0; nt < 4; ++nt)
        acc[i][nt] = __builtin_amdgcn_mfma_f32_16x16x32_bf16(Af[nt], u.v, acc[i][nt], 0, 0, 0);
    }
  }

  // epilogue: ReLU, pack -> conv2 MFMA (b2 folded into C-init) -> ReLU, store
  v8s w2f[4][2];
#pragma unroll
  for (int nt = 0; nt < 4; ++nt)
#pragma unroll
    for (int mt2 = 0; mt2 < 2; ++mt2)
      w2f[nt][mt2] = ((const v8s*)(wsus + PK2_US))[(nt * 2 + mt2) * 64 + lane];
  float4 b2q[2];
#pragma unroll
  for (int mt2 = 0; mt2 < 2; ++mt2)
    b2q[mt2] = *(const float4*)(wsf + B2F_F + mt2 * 16 + quad * 4);

#pragma unroll
  for (int i = 0; i < 4; ++i) {
    v4f a2[2];
    a2[0] = (v4f){b2q[0].x, b2q[0].y, b2q[0].z, b2q[0].w};
    a2[1] = (v4f){b2q[1].x, b2q[1].y, b2q[1].z, b2q[1].w};
#pragma unroll
    for (int nt = 0; nt < 4; ++nt) {
      float r0 = fmaxf(acc[i][nt][0], 0.f);
      float r1 = fmaxf(acc[i][nt][1], 0.f);
      float r2 = fmaxf(acc[i][nt][2], 0.f);
      float r3 = fmaxf(acc[i][nt][3], 0.f);
      unsigned int u0 = cvtpk(r0, r1), u1 = cvtpk(r2, r3);
      union { unsigned int q[4]; v8s v; } bu;
      bu.q[0] = u0; bu.q[1] = u1; bu.q[2] = u0; bu.q[3] = u1;
#pragma unroll
      for (int mt2 = 0; mt2 < 2; ++mt2)
        a2[mt2] = __builtin_amdgcn_mfma_f32_16x16x32_bf16(w2f[nt][mt2], bu.v, a2[mt2], 0, 0, 0);
    }
    int pix = pix0_[i] + lc;
    int gy = y0 + (pix >> 5), gx = x0 + (pix & 31);
    ushort_t* dst = h2 + (((b * 256 + gy) * 256 + gx) << 5) + (quad << 2);
#pragma unroll
    for (int mt2 = 0; mt2 < 2; ++mt2) {
      float v0 = fmaxf(a2[mt2][0], 0.f);
      float v1 = fmaxf(a2[mt2][1], 0.f);
      float v2 = fmaxf(a2[mt2][2], 0.f);
      float v3 = fmaxf(a2[mt2][3], 0.f);
      unsigned long long q =
          (unsigned long long)cvtpk(v0, v1) |
          ((unsigned long long)cvtpk(v2, v3) << 32);
      *(unsigned long long*)(dst + mt2 * 16) = q;
    }
  }
}

// ---------------- K3: MFMA conv5x5(32->4) via dx-in-N trick ----------------
// r2 kernel body (proven) + image-per-XCD block swizzle: 1D grid of 2048,
// bid&7 selects the XCD (round-robin dispatch), each XCD owns 2 images and
// walks their 128 tiles row-major -> y-neighbor halo re-reads of h2 hit that
// XCD's L2 instead of HBM.  Pure bijective index remap; no semantic change.
__global__ __launch_bounds__(256, 3) void k_conv3(
    const ushort_t* __restrict__ h2, const ushort_t* __restrict__ wsus,
    const float* __restrict__ wsf, void* __restrict__ out,
    const int* __restrict__ flag) {
  __shared__ __align__(16) ushort_t patch[20 * 1160];  // [y 20][x 36][ic 32] + 8 pad/row
  const int bid = blockIdx.x;
  const int xcd = bid & 7, qq = bid >> 3;        // qq 0..255
  const int b  = xcd * 2 + (qq >> 7);            // image 0..15
  const int tt = qq & 127;                       // tile in image, row-major
  const int x0 = (tt & 7) * 32, y0 = (tt >> 3) * 16;
  const int tid = threadIdx.x;

  for (int e = tid; e < 720; e += 256) {
    int yy = e / 36, xx = e - yy * 36;
    int gy = y0 + yy - 2, gx = x0 + xx - 2;
    ushort_t* dst = patch + yy * 1160 + xx * 32;
    if (gy >= 0 && gy < 256 && gx >= 0 && gx < 256) {
      const ushort_t* src = h2 + (((b * 256 + gy) * 256 + gx) << 5);
#pragma unroll
      for (int c = 0; c < 4; ++c)
        *(float4*)(dst + c * 8) = *(const float4*)(src + c * 8);
    } else {
      float4 z = make_float4(0.f, 0.f, 0.f, 0.f);
#pragma unroll
      for (int c = 0; c < 4; ++c) *(float4*)(dst + c * 8) = z;
    }
  }

  const int lane = tid & 63, wave = tid >> 6;
  const int quad = lane >> 4, lc = lane & 15;

  // preload conv3 weight frags ks 0..31 into registers (32 x v8s = 128 VGPR)
  const v8s* __restrict__ Bp3 = (const v8s*)(wsus + PK3_US);
  v8s Wf[32];
#pragma unroll
  for (int ks = 0; ks < 32; ++ks) Wf[ks] = Bp3[ks * 64 + lane];
  __syncthreads();

  // bias b3 folded into accumulator init
  float b3v = (wsf + B3F_F)[lc & 3];
  v4f acc[2];
  acc[0] = (v4f){b3v, b3v, b3v, b3v};
  acc[1] = (v4f){b3v, b3v, b3v, b3v};

#pragma unroll
  for (int ks = 0; ks < 40; ++ks) {
    int ky = ks >> 3, j = ks & 7;
    int rowoff = (lc + ky) * 1160 + j * 32 + quad * 8;
    v8s Bf = (ks < 32) ? Wf[ks] : Bp3[ks * 64 + lane];
#pragma unroll
    for (int i = 0; i < 2; ++i) {
      int q = wave * 2 + i;
      v8s Af = *(const v8s*)(patch + rowoff + q * 128);
      acc[i] = __builtin_amdgcn_mfma_f32_16x16x32_bf16(Af, Bf, acc[i], 0, 0, 0);
    }
  }

  // epilogue: C/D row=quad*4+r -> y_local, col=lc -> (dx=lc>>2, oc=lc&3)
  const int fl = flag[0];
#pragma unroll
  for (int i = 0; i < 2; ++i) {
    int q = wave * 2 + i;
#pragma unroll
    for (int r = 0; r < 4; ++r) {
      int gy = y0 + (quad << 2) + r;
      int gx = x0 + (q << 2) + (lc >> 2);
      int idx = (((b * 256 + gy) * 256 + gx) << 2) + (lc & 3);
      float vv = acc[i][r];
      if (fl) ((ushort_t*)out)[idx] = f2us(vv);
      else    ((float*)out)[idx] = vv;
    }
  }
}

// ---------------------------------------------------------------------------
extern "C" void kernel_launch(void* const* d_in, const int* in_sizes, int n_in,
                              void* d_out, int out_size, void* d_ws, size_t ws_size,
                              hipStream_t stream) {
  const void* x  = d_in[0];
  const void* w1 = d_in[1];
  const void* b1 = d_in[2];
  const void* w2 = d_in[3];
  const void* b2 = d_in[4];
  const void* w3 = d_in[5];
  const void* b3 = d_in[6];

  ushort_t* wsus = (ushort_t*)d_ws;
  float* wsf = (float*)d_ws;
  int* flag = (int*)((float*)d_ws + FLAG_I);
  ushort_t* up = wsus + UP_US;
  ushort_t* h2 = wsus + H2_US;

  k_cvt<<<(CVT_TOTAL + 255) / 256, 256, 0, stream>>>(x, w1, b1, w2, b2, w3, b3,
                                                     wsus, wsf, flag);
  k_upscale<<<4096, 256, 0, stream>>>(x, up, wsf, flag);
  k_conv12<<<dim3(8, 16, 16), 512, 0, stream>>>(up, wsus, wsf, h2);
  k_conv3<<<2048, 256, 0, stream>>>(h2, wsus, wsf, d_out, flag);
}

// Round 6
// 152.673 us; speedup vs baseline: 3.2696x; 1.0574x over previous
//
#include <hip/hip_runtime.h>
#include <hip/hip_bf16.h>

typedef unsigned short ushort_t;
typedef __attribute__((ext_vector_type(8))) short v8s;   // 8 bf16 = 4 VGPR (MFMA A/B)
typedef __attribute__((ext_vector_type(4))) float v4f;   // MFMA C/D

// ---------------------------------------------------------------------------
// ws layout (ushort indices unless noted):
//   pack1 [0, 22528)        conv1 A-frags (weights), dense K: [ks 11][nt 4][lane 64][8]
//   pack2 [22528, 26624)    conv2 A-frags hi|lo-in-j: [nt 4][mt2 2][lane 64][8]
//   pack3 [26624, 47104)    conv3 B-frags (hi only): [ks 40][lane 64][8]
//   floats at us 47104 (float idx 23552):
#define B1F_F   23552      // 64
#define B2F_F   23616      // 32
#define B3F_F   23648      // 4
#define WTAB_F  23652      // 32 (8 phases x 4 taps)
#define FLAG_I  23684      // int (1 = bf16 inputs/outputs, 0 = fp32)
#define PK1_US  0
#define PK2_US  22528
#define PK3_US  26624
#define H2_US   4242560    // bf16 NHWC [16][256][256][32] (32M us = 64 MB)
#define CVT_TOTAL (47104 + 132)
// ---------------------------------------------------------------------------

__device__ __forceinline__ ushort_t f2us(float v) {
  __hip_bfloat16 h = __float2bfloat16(v);
  return *reinterpret_cast<ushort_t*>(&h);
}
__device__ __forceinline__ float us2f(unsigned int u) { return __uint_as_float(u << 16); }

// RNE-pack two finite floats into two bf16 (lo = a, hi = b). Bit-exact RNE.
__device__ __forceinline__ unsigned int bfpair(float a, float b) {
  unsigned int ua = __float_as_uint(a), ub = __float_as_uint(b);
  ua += 0x7fffu + ((ua >> 16) & 1u);
  ub += 0x7fffu + ((ub >> 16) & 1u);
  return (ua >> 16) | (ub & 0xffff0000u);
}

// HW packed f32->bf16 (RNE under default MODE.round) — 1 VALU op vs ~7 for bfpair.
__device__ __forceinline__ unsigned int cvtpk(float a, float b) {
  unsigned int r;
  asm("v_cvt_pk_bf16_f32 %0, %1, %2" : "=v"(r) : "v"(a), "v"(b));
  return r;
}

// direct global -> LDS DMA, 16 B per lane (dest must be linear in lane order)
__device__ __forceinline__ void gload_lds16(const void* g, void* l) {
  __builtin_amdgcn_global_load_lds(
      (const __attribute__((address_space(1))) void*)g,
      (__attribute__((address_space(3))) void*)l, 16, 0, 0);
}

__device__ __forceinline__ float load_in(const void* p, int i, int isbf16) {
  if (isbf16) return us2f(((const unsigned short*)p)[i]);
  return ((const float*)p)[i];
}
__device__ __forceinline__ float4 load_in4(const void* p, int i4, int isbf16) {
  if (isbf16) {
    unsigned long long q = *(const unsigned long long*)((const unsigned short*)p + i4);
    return make_float4(us2f((unsigned int)(q & 0xffff)),
                       us2f((unsigned int)((q >> 16) & 0xffff)),
                       us2f((unsigned int)((q >> 32) & 0xffff)),
                       us2f((unsigned int)((q >> 48) & 0xffff)));
  }
  return *(const float4*)((const float*)p + i4);
}

__device__ __forceinline__ float cubicw(float d) {
  const float Ac = -0.75f;
  d = fabsf(d);
  float d2 = d * d, d3 = d2 * d;
  if (d <= 1.f) return (Ac + 2.f) * d3 - (Ac + 3.f) * d2 + 1.f;
  if (d < 2.f)  return Ac * d3 - 5.f * Ac * d2 + 8.f * Ac * d - 4.f * Ac;
  return 0.f;
}

// ---------------- K_cvt: inline dtype probe + build weight packs -----------
__global__ __launch_bounds__(256) void k_cvt(
    const void* __restrict__ x,
    const void* __restrict__ w1, const void* __restrict__ b1,
    const void* __restrict__ w2, const void* __restrict__ b2,
    const void* __restrict__ w3, const void* __restrict__ b3,
    ushort_t* __restrict__ wsus, float* __restrict__ wsf,
    int* __restrict__ flag) {
  __shared__ int scnt;
  const int tid = threadIdx.x;
  if (tid == 0) scnt = 0;
  __syncthreads();
  {
    const unsigned short* xr = (const unsigned short*)x;
    int c = 0;
    for (int s = tid; s < 512; s += 256) {
      unsigned short h = xr[2 * s];
      int e = (h >> 7) & 0xFF;
      if (e >= 110 && e <= 135) c++;
    }
    if (c) atomicAdd(&scnt, c);
  }
  __syncthreads();
  const int f = (scnt >= 256) ? 1 : 0;
  if (blockIdx.x == 0 && tid == 0) flag[0] = f;

  int i = blockIdx.x * 256 + tid;
  if (i >= CVT_TOTAL) return;
  if (i < 22528) {
    // pack1 dense: k = ks*32+quad*8+j; k<324: tap=k>>2 (ky=tap/9,kx=tap%9), ic=k&3
    int j  = i & 7;
    int l  = (i >> 3) & 63;
    int nt = (i >> 9) & 3;
    int ks = i >> 11;
    int k  = ks * 32 + ((l >> 4) & 3) * 8 + j;
    int oc = nt * 16 + (l & 15);
    float v = 0.f;
    if (k < 324) {
      int tap = k >> 2, ic = k & 3;
      int ky = tap / 9, kx = tap - ky * 9;
      v = load_in(w1, ((oc * 4 + ic) * 9 + ky) * 9 + kx, f);
    }
    wsus[PK1_US + i] = f2us(v);
    return;
  }
  if (i < 26624) {
    // pack2: [nt][mt2][lane][8]; j<4 = hi(w2), j>=4 = lo residual
    int t = i - 22528;
    int j   = t & 7;
    int l   = (t >> 3) & 63;
    int mt2 = (t >> 9) & 1;
    int nt  = (t >> 10) & 3;
    int oc1 = nt * 16 + ((l >> 4) & 3) * 4 + (j & 3);
    int oc2 = mt2 * 16 + (l & 15);
    float w = load_in(w2, oc2 * 64 + oc1, f);
    float hi = us2f(f2us(w));
    wsus[PK2_US + t] = (j < 4) ? f2us(w) : f2us(w - hi);
    return;
  }
  if (i < 47104) {
    // pack3 (hi only): [ks 40][lane][8]; k=ky*256+jj*32+ic; n=dx*4+oc
    int t = i - 26624;
    int j8 = t & 7;
    int l  = (t >> 3) & 63;
    int ks = t >> 9;
    int k  = ks * 32 + ((l >> 4) & 3) * 8 + j8;
    int n  = l & 15;
    int ky = k >> 8, jj = (k >> 5) & 7, ic = k & 31;
    int dx = n >> 2, oc = n & 3;
    int kx = jj - dx;
    float w = 0.f;
    if (kx >= 0 && kx <= 4)
      w = load_in(w3, ((oc * 32 + ic) * 5 + ky) * 5 + kx, f);
    wsus[PK3_US + t] = f2us(w);
    return;
  }
  int t = i - 47104;
  if (t < 64) { wsf[B1F_F + t] = load_in(b1, t, f); return; }
  if (t < 96) { wsf[B2F_F + (t - 64)] = load_in(b2, t - 64, f); return; }
  if (t < 100) { wsf[B3F_F + (t - 96)] = load_in(b3, t - 96, f); return; }
  if (t < 132) {
    int p = (t - 100) >> 2, a = (t - 100) & 3;
    float frac = (p + 0.5f) * 0.125f - 0.5f;
    float fl = floorf(frac);
    float tt = frac - fl;
    wsf[WTAB_F + (t - 100)] = cubicw(tt - (float)(a - 1));
  }
}

// ---------------- K2: fused bicubic-x8 + conv9x9(4->64)+ReLU + conv1x1 ----
// r2-proven MFMA structure (49.4us, FETCH 7.9MB, WRITE 64MB clean) with the
// upscale FUSED into patch staging: each block computes its 40x24 up-patch
// directly from x (16KB/image, L1/L2-hot) with arithmetic bit-identical to
// the old k_upscale (same wtab, same FMA order, same bfpair pack).  Kills
// the separate 1M-thread upscale kernel (~10-12us) and the up round trip.
// Staging VALU overlaps the async pack1 DMA already in flight.
// NOTE (r4 lesson): acc[4][4] fits the (512,4) 128-reg budget; acc[8][4]
// does NOT (spills -> 2GB scratch).  NOTE (r5 lesson): no XCD swizzles
// based on assumed dispatch order.
__global__ __launch_bounds__(512, 4) void k_conv12(
    const void* __restrict__ x, const ushort_t* __restrict__ wsus,
    const float* __restrict__ wsf, ushort_t* __restrict__ h2,
    const int* __restrict__ flag) {
  __shared__ __align__(16) ushort_t patchA[24 * 40 * 4];  // 7680 B
  __shared__ __align__(16) ushort_t pack1L[22528];        // 45056 B
  const int b  = blockIdx.z;
  const int x0 = blockIdx.x * 32, y0 = blockIdx.y * 16;
  const int tid = threadIdx.x;
  const int f = flag[0];

  // stage pack1 -> LDS via direct DMA (2816 x 16B; dest linear in lane order)
  {
    const ushort_t* src = wsus + PK1_US;
#pragma unroll
    for (int i = 0; i < 6; ++i) {
      int e = tid + i * 512;
      if (e < 2816)                              // wave-uniform guard
        gload_lds16(src + e * 8, pack1L + e * 8);
    }
  }
  // compute 24x40 patch inline (bicubic x8 from x; bit-identical to old
  // k_upscale: same wtab, same fmaf order, same bfpair) -> LDS, zero border
  {
    const float* wt = wsf + WTAB_F;
#pragma unroll
    for (int rep = 0; rep < 2; ++rep) {
      int e = tid + rep * 512;                  // need 960; rep1: waves 0..6
      if (e < 960) {
        int yy = e / 40, xx = e - yy * 40;
        int gy = y0 + yy - 4, gx = x0 + xx - 4;
        unsigned long long q = 0ull;
        if (gy >= 0 && gy < 256 && gx >= 0 && gx < 256) {
          int px = gx & 7, py = gy & 7;
          float4 wx = *(const float4*)(wt + px * 4);
          float4 wy = *(const float4*)(wt + py * 4);
          float wya[4] = {wy.x, wy.y, wy.z, wy.w};
          int bx = (gx >> 3) + ((px >= 4) ? 0 : -1);
          int by = (gy >> 3) + ((py >= 4) ? 0 : -1);
          int ix0 = min(max(bx - 1, 0), 31), ix1 = min(max(bx, 0), 31);
          int ix2 = min(max(bx + 1, 0), 31), ix3 = min(max(bx + 2, 0), 31);
          float ax = 0.f, ay = 0.f, az = 0.f, aw = 0.f;
#pragma unroll
          for (int a = 0; a < 4; a++) {
            int iy = min(max(by + a - 1, 0), 31);
            int rowb = (b * 32 + iy) * 32;
            float4 p0 = load_in4(x, (rowb + ix0) * 4, f);
            float4 p1 = load_in4(x, (rowb + ix1) * 4, f);
            float4 p2 = load_in4(x, (rowb + ix2) * 4, f);
            float4 p3 = load_in4(x, (rowb + ix3) * 4, f);
            float rx = wx.x * p0.x + wx.y * p1.x + wx.z * p2.x + wx.w * p3.x;
            float ry = wx.x * p0.y + wx.y * p1.y + wx.z * p2.y + wx.w * p3.y;
            float rz = wx.x * p0.z + wx.y * p1.z + wx.z * p2.z + wx.w * p3.z;
            float rw = wx.x * p0.w + wx.y * p1.w + wx.z * p2.w + wx.w * p3.w;
            ax = fmaf(wya[a], rx, ax); ay = fmaf(wya[a], ry, ay);
            az = fmaf(wya[a], rz, az); aw = fmaf(wya[a], rw, aw);
          }
          q = (unsigned long long)bfpair(ax, ay) |
              ((unsigned long long)bfpair(az, aw) << 32);
        }
        *(unsigned long long*)(patchA + e * 4) = q;
      }
    }
  }
  __syncthreads();

  const int lane = tid & 63, wave = tid >> 6;
  const int quad = lane >> 4, lc = lane & 15;
  int base_m[4], pix0_[4];
#pragma unroll
  for (int i = 0; i < 4; ++i) {
    int mt = wave * 4 + i;                   // 0..31
    int py = mt >> 1, pxh = (mt & 1) << 4;   // py 0..15, pxh 0/16
    base_m[i] = (py * 40 + pxh + lc) << 2;   // ushort idx of (py, pxh+lc, ic0)
    pix0_[i] = py * 32 + pxh;
  }

  // bias b1 -> accumulator init (C-in of the first MFMA)
  float4 b1q[4];
#pragma unroll
  for (int nt = 0; nt < 4; ++nt)
    b1q[nt] = *(const float4*)(wsf + B1F_F + nt * 16 + quad * 4);
  v4f acc[4][4];
#pragma unroll
  for (int i = 0; i < 4; ++i)
#pragma unroll
    for (int nt = 0; nt < 4; ++nt)
      acc[i][nt] = (v4f){b1q[nt].x, b1q[nt].y, b1q[nt].z, b1q[nt].w};

  const v8s* __restrict__ Ap1 = (const v8s*)pack1L;
#pragma unroll
  for (int ks = 0; ks < 11; ++ks) {
    v8s Af[4];
#pragma unroll
    for (int nt = 0; nt < 4; ++nt) Af[nt] = Ap1[(ks * 4 + nt) * 64 + lane];
    int tap0 = ks * 8 + quad * 2;
    int tap1 = min(tap0 + 1, 80);
    tap0 = min(tap0, 80);
    int ky0 = tap0 / 9, kx0 = tap0 - ky0 * 9;
    int ky1 = tap1 / 9, kx1 = tap1 - ky1 * 9;
    int off0 = (ky0 * 40 + kx0) << 2;
    int off1 = (ky1 * 40 + kx1) << 2;
#pragma unroll
    for (int i = 0; i < 4; ++i) {
      union { unsigned long long q[2]; v8s v; } u;
      u.q[0] = *(const unsigned long long*)(patchA + base_m[i] + off0);
      u.q[1] = *(const unsigned long long*)(patchA + base_m[i] + off1);
#pragma unroll
      for (int nt = 0; nt < 4; ++nt)
        acc[i][nt] = __builtin_amdgcn_mfma_f32_16x16x32_bf16(Af[nt], u.v, acc[i][nt], 0, 0, 0);
    }
  }

  // epilogue: ReLU, pack -> conv2 MFMA (b2 folded into C-init) -> ReLU, store
  v8s w2f[4][2];
#pragma unroll
  for (int nt = 0; nt < 4; ++nt)
#pragma unroll
    for (int mt2 = 0; mt2 < 2; ++mt2)
      w2f[nt][mt2] = ((const v8s*)(wsus + PK2_US))[(nt * 2 + mt2) * 64 + lane];
  float4 b2q[2];
#pragma unroll
  for (int mt2 = 0; mt2 < 2; ++mt2)
    b2q[mt2] = *(const float4*)(wsf + B2F_F + mt2 * 16 + quad * 4);

#pragma unroll
  for (int i = 0; i < 4; ++i) {
    v4f a2[2];
    a2[0] = (v4f){b2q[0].x, b2q[0].y, b2q[0].z, b2q[0].w};
    a2[1] = (v4f){b2q[1].x, b2q[1].y, b2q[1].z, b2q[1].w};
#pragma unroll
    for (int nt = 0; nt < 4; ++nt) {
      float r0 = fmaxf(acc[i][nt][0], 0.f);
      float r1 = fmaxf(acc[i][nt][1], 0.f);
      float r2 = fmaxf(acc[i][nt][2], 0.f);
      float r3 = fmaxf(acc[i][nt][3], 0.f);
      unsigned int u0 = cvtpk(r0, r1), u1 = cvtpk(r2, r3);
      union { unsigned int q[4]; v8s v; } bu;
      bu.q[0] = u0; bu.q[1] = u1; bu.q[2] = u0; bu.q[3] = u1;
#pragma unroll
      for (int mt2 = 0; mt2 < 2; ++mt2)
        a2[mt2] = __builtin_amdgcn_mfma_f32_16x16x32_bf16(w2f[nt][mt2], bu.v, a2[mt2], 0, 0, 0);
    }
    int pix = pix0_[i] + lc;
    int gy = y0 + (pix >> 5), gx = x0 + (pix & 31);
    ushort_t* dst = h2 + (((b * 256 + gy) * 256 + gx) << 5) + (quad << 2);
#pragma unroll
    for (int mt2 = 0; mt2 < 2; ++mt2) {
      float v0 = fmaxf(a2[mt2][0], 0.f);
      float v1 = fmaxf(a2[mt2][1], 0.f);
      float v2 = fmaxf(a2[mt2][2], 0.f);
      float v3 = fmaxf(a2[mt2][3], 0.f);
      unsigned long long q =
          (unsigned long long)cvtpk(v0, v1) |
          ((unsigned long long)cvtpk(v2, v3) << 32);
      *(unsigned long long*)(dst + mt2 * 16) = q;
    }
  }
}

// ---------------- K3: MFMA conv5x5(32->4) via dx-in-N trick ----------------
// r2-exact body (proven best): grid dim3(8,16,16), Wf[0..31] in registers,
// ks 32..39 streamed from L2, launch_bounds(256,3).
__global__ __launch_bounds__(256, 3) void k_conv3(
    const ushort_t* __restrict__ h2, const ushort_t* __restrict__ wsus,
    const float* __restrict__ wsf, void* __restrict__ out,
    const int* __restrict__ flag) {
  __shared__ __align__(16) ushort_t patch[20 * 1160];  // [y 20][x 36][ic 32] + 8 pad/row
  const int b  = blockIdx.z;
  const int x0 = blockIdx.x * 32, y0 = blockIdx.y * 16;
  const int tid = threadIdx.x;

  for (int e = tid; e < 720; e += 256) {
    int yy = e / 36, xx = e - yy * 36;
    int gy = y0 + yy - 2, gx = x0 + xx - 2;
    ushort_t* dst = patch + yy * 1160 + xx * 32;
    if (gy >= 0 && gy < 256 && gx >= 0 && gx < 256) {
      const ushort_t* src = h2 + (((b * 256 + gy) * 256 + gx) << 5);
#pragma unroll
      for (int c = 0; c < 4; ++c)
        *(float4*)(dst + c * 8) = *(const float4*)(src + c * 8);
    } else {
      float4 z = make_float4(0.f, 0.f, 0.f, 0.f);
#pragma unroll
      for (int c = 0; c < 4; ++c) *(float4*)(dst + c * 8) = z;
    }
  }

  const int lane = tid & 63, wave = tid >> 6;
  const int quad = lane >> 4, lc = lane & 15;

  // preload conv3 weight frags ks 0..31 into registers (32 x v8s = 128 VGPR)
  const v8s* __restrict__ Bp3 = (const v8s*)(wsus + PK3_US);
  v8s Wf[32];
#pragma unroll
  for (int ks = 0; ks < 32; ++ks) Wf[ks] = Bp3[ks * 64 + lane];
  __syncthreads();

  // bias b3 folded into accumulator init
  float b3v = (wsf + B3F_F)[lc & 3];
  v4f acc[2];
  acc[0] = (v4f){b3v, b3v, b3v, b3v};
  acc[1] = (v4f){b3v, b3v, b3v, b3v};

#pragma unroll
  for (int ks = 0; ks < 40; ++ks) {
    int ky = ks >> 3, j = ks & 7;
    int rowoff = (lc + ky) * 1160 + j * 32 + quad * 8;
    v8s Bf = (ks < 32) ? Wf[ks] : Bp3[ks * 64 + lane];
#pragma unroll
    for (int i = 0; i < 2; ++i) {
      int q = wave * 2 + i;
      v8s Af = *(const v8s*)(patch + rowoff + q * 128);
      acc[i] = __builtin_amdgcn_mfma_f32_16x16x32_bf16(Af, Bf, acc[i], 0, 0, 0);
    }
  }

  // epilogue: C/D row=quad*4+r -> y_local, col=lc -> (dx=lc>>2, oc=lc&3)
  const int fl = flag[0];
#pragma unroll
  for (int i = 0; i < 2; ++i) {
    int q = wave * 2 + i;
#pragma unroll
    for (int r = 0; r < 4; ++r) {
      int gy = y0 + (quad << 2) + r;
      int gx = x0 + (q << 2) + (lc >> 2);
      int idx = (((b * 256 + gy) * 256 + gx) << 2) + (lc & 3);
      float vv = acc[i][r];
      if (fl) ((ushort_t*)out)[idx] = f2us(vv);
      else    ((float*)out)[idx] = vv;
    }
  }
}

// ---------------------------------------------------------------------------
extern "C" void kernel_launch(void* const* d_in, const int* in_sizes, int n_in,
                              void* d_out, int out_size, void* d_ws, size_t ws_size,
                              hipStream_t stream) {
  const void* x  = d_in[0];
  const void* w1 = d_in[1];
  const void* b1 = d_in[2];
  const void* w2 = d_in[3];
  const void* b2 = d_in[4];
  const void* w3 = d_in[5];
  const void* b3 = d_in[6];

  ushort_t* wsus = (ushort_t*)d_ws;
  float* wsf = (float*)d_ws;
  int* flag = (int*)((float*)d_ws + FLAG_I);
  ushort_t* h2 = wsus + H2_US;

  k_cvt<<<(CVT_TOTAL + 255) / 256, 256, 0, stream>>>(x, w1, b1, w2, b2, w3, b3,
                                                     wsus, wsf, flag);
  k_conv12<<<dim3(8, 16, 16), 512, 0, stream>>>(x, wsus, wsf, h2, flag);
  k_conv3<<<dim3(8, 16, 16), 256, 0, stream>>>(h2, wsus, wsf, d_out, flag);
}

// Round 7
// 148.185 us; speedup vs baseline: 3.3686x; 1.0303x over previous
//
#include <hip/hip_runtime.h>
#include <hip/hip_bf16.h>

typedef unsigned short ushort_t;
typedef __attribute__((ext_vector_type(8))) short v8s;   // 8 bf16 = 4 VGPR (MFMA A/B)
typedef __attribute__((ext_vector_type(4))) float v4f;   // MFMA C/D

// ---------------------------------------------------------------------------
// ws layout (ushort indices unless noted):
//   pack1 [0, 22528)        conv1 A-frags (weights), dense K: [ks 11][nt 4][lane 64][8]
//   pack2 [22528, 26624)    conv2 A-frags hi|lo-in-j: [nt 4][mt2 2][lane 64][8]
//   pack3 [26624, 47104)    conv3 B-frags (hi only): [ks 40][lane 64][8]
//   floats at us 47104 (float idx 23552):
#define B1F_F   23552      // 64
#define B2F_F   23616      // 32
#define B3F_F   23648      // 4
#define WTAB_F  23652      // 32 (8 phases x 4 taps)
#define FLAG_I  23684      // int (1 = bf16 inputs/outputs, 0 = fp32)
#define PK1_US  0
#define PK2_US  22528
#define PK3_US  26624
#define H2_US   4242560    // bf16 NHWC [16][256][256][32] (32M us = 64 MB)
#define CVT_TOTAL (47104 + 132)
// ---------------------------------------------------------------------------

__device__ __forceinline__ ushort_t f2us(float v) {
  __hip_bfloat16 h = __float2bfloat16(v);
  return *reinterpret_cast<ushort_t*>(&h);
}
__device__ __forceinline__ float us2f(unsigned int u) { return __uint_as_float(u << 16); }

// RNE-pack two finite floats into two bf16 (lo = a, hi = b). Bit-exact RNE.
__device__ __forceinline__ unsigned int bfpair(float a, float b) {
  unsigned int ua = __float_as_uint(a), ub = __float_as_uint(b);
  ua += 0x7fffu + ((ua >> 16) & 1u);
  ub += 0x7fffu + ((ub >> 16) & 1u);
  return (ua >> 16) | (ub & 0xffff0000u);
}

// HW packed f32->bf16 (RNE under default MODE.round) — 1 VALU op vs ~7 for bfpair.
__device__ __forceinline__ unsigned int cvtpk(float a, float b) {
  unsigned int r;
  asm("v_cvt_pk_bf16_f32 %0, %1, %2" : "=v"(r) : "v"(a), "v"(b));
  return r;
}

// direct global -> LDS DMA, 16 B per lane (dest must be linear in lane order)
__device__ __forceinline__ void gload_lds16(const void* g, void* l) {
  __builtin_amdgcn_global_load_lds(
      (const __attribute__((address_space(1))) void*)g,
      (__attribute__((address_space(3))) void*)l, 16, 0, 0);
}

__device__ __forceinline__ float load_in(const void* p, int i, int isbf16) {
  if (isbf16) return us2f(((const unsigned short*)p)[i]);
  return ((const float*)p)[i];
}
__device__ __forceinline__ float4 load_in4(const void* p, int i4, int isbf16) {
  if (isbf16) {
    unsigned long long q = *(const unsigned long long*)((const unsigned short*)p + i4);
    return make_float4(us2f((unsigned int)(q & 0xffff)),
                       us2f((unsigned int)((q >> 16) & 0xffff)),
                       us2f((unsigned int)((q >> 32) & 0xffff)),
                       us2f((unsigned int)((q >> 48) & 0xffff)));
  }
  return *(const float4*)((const float*)p + i4);
}

__device__ __forceinline__ float cubicw(float d) {
  const float Ac = -0.75f;
  d = fabsf(d);
  float d2 = d * d, d3 = d2 * d;
  if (d <= 1.f) return (Ac + 2.f) * d3 - (Ac + 3.f) * d2 + 1.f;
  if (d < 2.f)  return Ac * d3 - 5.f * Ac * d2 + 8.f * Ac * d - 4.f * Ac;
  return 0.f;
}

// ---------------- K_cvt: inline dtype probe + build weight packs -----------
__global__ __launch_bounds__(256) void k_cvt(
    const void* __restrict__ x,
    const void* __restrict__ w1, const void* __restrict__ b1,
    const void* __restrict__ w2, const void* __restrict__ b2,
    const void* __restrict__ w3, const void* __restrict__ b3,
    ushort_t* __restrict__ wsus, float* __restrict__ wsf,
    int* __restrict__ flag) {
  __shared__ int scnt;
  const int tid = threadIdx.x;
  if (tid == 0) scnt = 0;
  __syncthreads();
  {
    const unsigned short* xr = (const unsigned short*)x;
    int c = 0;
    for (int s = tid; s < 512; s += 256) {
      unsigned short h = xr[2 * s];
      int e = (h >> 7) & 0xFF;
      if (e >= 110 && e <= 135) c++;
    }
    if (c) atomicAdd(&scnt, c);
  }
  __syncthreads();
  const int f = (scnt >= 256) ? 1 : 0;
  if (blockIdx.x == 0 && tid == 0) flag[0] = f;

  int i = blockIdx.x * 256 + tid;
  if (i >= CVT_TOTAL) return;
  if (i < 22528) {
    // pack1 dense: k = ks*32+quad*8+j; k<324: tap=k>>2 (ky=tap/9,kx=tap%9), ic=k&3
    int j  = i & 7;
    int l  = (i >> 3) & 63;
    int nt = (i >> 9) & 3;
    int ks = i >> 11;
    int k  = ks * 32 + ((l >> 4) & 3) * 8 + j;
    int oc = nt * 16 + (l & 15);
    float v = 0.f;
    if (k < 324) {
      int tap = k >> 2, ic = k & 3;
      int ky = tap / 9, kx = tap - ky * 9;
      v = load_in(w1, ((oc * 4 + ic) * 9 + ky) * 9 + kx, f);
    }
    wsus[PK1_US + i] = f2us(v);
    return;
  }
  if (i < 26624) {
    // pack2: [nt][mt2][lane][8]; j<4 = hi(w2), j>=4 = lo residual
    int t = i - 22528;
    int j   = t & 7;
    int l   = (t >> 3) & 63;
    int mt2 = (t >> 9) & 1;
    int nt  = (t >> 10) & 3;
    int oc1 = nt * 16 + ((l >> 4) & 3) * 4 + (j & 3);
    int oc2 = mt2 * 16 + (l & 15);
    float w = load_in(w2, oc2 * 64 + oc1, f);
    float hi = us2f(f2us(w));
    wsus[PK2_US + t] = (j < 4) ? f2us(w) : f2us(w - hi);
    return;
  }
  if (i < 47104) {
    // pack3 (hi only): [ks 40][lane][8]; k=ky*256+jj*32+ic; n=dx*4+oc
    int t = i - 26624;
    int j8 = t & 7;
    int l  = (t >> 3) & 63;
    int ks = t >> 9;
    int k  = ks * 32 + ((l >> 4) & 3) * 8 + j8;
    int n  = l & 15;
    int ky = k >> 8, jj = (k >> 5) & 7, ic = k & 31;
    int dx = n >> 2, oc = n & 3;
    int kx = jj - dx;
    float w = 0.f;
    if (kx >= 0 && kx <= 4)
      w = load_in(w3, ((oc * 32 + ic) * 5 + ky) * 5 + kx, f);
    wsus[PK3_US + t] = f2us(w);
    return;
  }
  int t = i - 47104;
  if (t < 64) { wsf[B1F_F + t] = load_in(b1, t, f); return; }
  if (t < 96) { wsf[B2F_F + (t - 64)] = load_in(b2, t - 64, f); return; }
  if (t < 100) { wsf[B3F_F + (t - 96)] = load_in(b3, t - 96, f); return; }
  if (t < 132) {
    int p = (t - 100) >> 2, a = (t - 100) & 3;
    float frac = (p + 0.5f) * 0.125f - 0.5f;
    float fl = floorf(frac);
    float tt = frac - fl;
    wsf[WTAB_F + (t - 100)] = cubicw(tt - (float)(a - 1));
  }
}

// ---------------- K2: fused bicubic-x8 + conv9x9(4->64)+ReLU + conv1x1 ----
// r2-proven MFMA structure; upscale fused into patch staging with 3-ROW
// SHARING: rows gy, gy+8, gy+16 have identical py (=gy&7, so same wy) and
// by(gy+8)=by(gy)+1, so 6 x-filtered source rows serve all 3 outputs.
// 320 threads x 3 px replaces 960 thread-px: ~42% less staging VALU+loads,
// arithmetic bit-identical (same x-filter expression, same y-fmaf chain,
// same bfpair) -> absmax must stay exactly 0.015625.
// NOTE (r4): acc[4][4] fits the (512,4) 128-reg budget; acc[8][4] spills.
// NOTE (r5): no XCD swizzles based on assumed dispatch order.
__global__ __launch_bounds__(512, 4) void k_conv12(
    const void* __restrict__ x, const ushort_t* __restrict__ wsus,
    const float* __restrict__ wsf, ushort_t* __restrict__ h2,
    const int* __restrict__ flag) {
  __shared__ __align__(16) ushort_t patchA[24 * 40 * 4];  // 7680 B
  __shared__ __align__(16) ushort_t pack1L[22528];        // 45056 B
  const int b  = blockIdx.z;
  const int x0 = blockIdx.x * 32, y0 = blockIdx.y * 16;
  const int tid = threadIdx.x;
  const int f = flag[0];

  // stage pack1 -> LDS via direct DMA (2816 x 16B; dest linear in lane order)
  {
    const ushort_t* src = wsus + PK1_US;
#pragma unroll
    for (int i = 0; i < 6; ++i) {
      int e = tid + i * 512;
      if (e < 2816)                              // wave-uniform guard
        gload_lds16(src + e * 8, pack1L + e * 8);
    }
  }
  // compute 24x40 patch inline (bicubic x8 from x, 3-row sharing) -> LDS.
  // thread e<320: column xx=e%40, base row yy=e/40 (0..7); outputs rows
  // yy, yy+8, yy+16.  VALU overlaps the pack1 DMA in flight.
  {
    const float* wt = wsf + WTAB_F;
    if (tid < 320) {
      int yy = tid / 40, xx = tid - yy * 40;
      int gy0 = y0 + yy - 4;                 // rows gy0, gy0+8, gy0+16
      int gx  = x0 + xx - 4;
      // x-side (shared by all 3 rows)
      int pxv = gx & 7;
      float4 wx = *(const float4*)(wt + pxv * 4);
      int bx = (gx >> 3) + ((pxv >= 4) ? 0 : -1);
      int ix0 = min(max(bx - 1, 0), 31), ix1 = min(max(bx, 0), 31);
      int ix2 = min(max(bx + 1, 0), 31), ix3 = min(max(bx + 2, 0), 31);
      // y-side: py identical for all 3 rows (mod-8); by increments by 1
      int pyv = gy0 & 7;
      float4 wy = *(const float4*)(wt + pyv * 4);
      float wya[4] = {wy.x, wy.y, wy.z, wy.w};
      int by0 = (gy0 >> 3) + ((pyv >= 4) ? 0 : -1);
      bool gxok = (gx >= 0 && gx < 256);
      // x-filter 6 source rows: j=0..5 -> source row clamp(by0-1+j)
      float fr[6][4];
#pragma unroll
      for (int j = 0; j < 6; ++j) {
        int iy = min(max(by0 - 1 + j, 0), 31);
        int rowb = (b * 32 + iy) * 32;
        float4 p0 = load_in4(x, (rowb + ix0) * 4, f);
        float4 p1 = load_in4(x, (rowb + ix1) * 4, f);
        float4 p2 = load_in4(x, (rowb + ix2) * 4, f);
        float4 p3 = load_in4(x, (rowb + ix3) * 4, f);
        fr[j][0] = wx.x * p0.x + wx.y * p1.x + wx.z * p2.x + wx.w * p3.x;
        fr[j][1] = wx.x * p0.y + wx.y * p1.y + wx.z * p2.y + wx.w * p3.y;
        fr[j][2] = wx.x * p0.z + wx.y * p1.z + wx.z * p2.z + wx.w * p3.z;
        fr[j][3] = wx.x * p0.w + wx.y * p1.w + wx.z * p2.w + wx.w * p3.w;
      }
      // y-combine: output o uses x-filtered rows j = o..o+3 (tap a -> o+a)
#pragma unroll
      for (int o = 0; o < 3; ++o) {
        int gy = gy0 + 8 * o;
        unsigned long long q = 0ull;
        if (gxok && gy >= 0 && gy < 256) {
          float ax = 0.f, ay = 0.f, az = 0.f, aw = 0.f;
#pragma unroll
          for (int a = 0; a < 4; a++) {
            ax = fmaf(wya[a], fr[o + a][0], ax);
            ay = fmaf(wya[a], fr[o + a][1], ay);
            az = fmaf(wya[a], fr[o + a][2], az);
            aw = fmaf(wya[a], fr[o + a][3], aw);
          }
          q = (unsigned long long)bfpair(ax, ay) |
              ((unsigned long long)bfpair(az, aw) << 32);
        }
        *(unsigned long long*)(patchA + ((yy + 8 * o) * 40 + xx) * 4) = q;
      }
    }
  }
  __syncthreads();

  const int lane = tid & 63, wave = tid >> 6;
  const int quad = lane >> 4, lc = lane & 15;
  int base_m[4], pix0_[4];
#pragma unroll
  for (int i = 0; i < 4; ++i) {
    int mt = wave * 4 + i;                   // 0..31
    int py = mt >> 1, pxh = (mt & 1) << 4;   // py 0..15, pxh 0/16
    base_m[i] = (py * 40 + pxh + lc) << 2;   // ushort idx of (py, pxh+lc, ic0)
    pix0_[i] = py * 32 + pxh;
  }

  // bias b1 -> accumulator init (C-in of the first MFMA)
  float4 b1q[4];
#pragma unroll
  for (int nt = 0; nt < 4; ++nt)
    b1q[nt] = *(const float4*)(wsf + B1F_F + nt * 16 + quad * 4);
  v4f acc[4][4];
#pragma unroll
  for (int i = 0; i < 4; ++i)
#pragma unroll
    for (int nt = 0; nt < 4; ++nt)
      acc[i][nt] = (v4f){b1q[nt].x, b1q[nt].y, b1q[nt].z, b1q[nt].w};

  const v8s* __restrict__ Ap1 = (const v8s*)pack1L;
#pragma unroll
  for (int ks = 0; ks < 11; ++ks) {
    v8s Af[4];
#pragma unroll
    for (int nt = 0; nt < 4; ++nt) Af[nt] = Ap1[(ks * 4 + nt) * 64 + lane];
    int tap0 = ks * 8 + quad * 2;
    int tap1 = min(tap0 + 1, 80);
    tap0 = min(tap0, 80);
    int ky0 = tap0 / 9, kx0 = tap0 - ky0 * 9;
    int ky1 = tap1 / 9, kx1 = tap1 - ky1 * 9;
    int off0 = (ky0 * 40 + kx0) << 2;
    int off1 = (ky1 * 40 + kx1) << 2;
#pragma unroll
    for (int i = 0; i < 4; ++i) {
      union { unsigned long long q[2]; v8s v; } u;
      u.q[0] = *(const unsigned long long*)(patchA + base_m[i] + off0);
      u.q[1] = *(const unsigned long long*)(patchA + base_m[i] + off1);
#pragma unroll
      for (int nt = 0; nt < 4; ++nt)
        acc[i][nt] = __builtin_amdgcn_mfma_f32_16x16x32_bf16(Af[nt], u.v, acc[i][nt], 0, 0, 0);
    }
  }

  // epilogue: ReLU, pack -> conv2 MFMA (b2 folded into C-init) -> ReLU, store
  v8s w2f[4][2];
#pragma unroll
  for (int nt = 0; nt < 4; ++nt)
#pragma unroll
    for (int mt2 = 0; mt2 < 2; ++mt2)
      w2f[nt][mt2] = ((const v8s*)(wsus + PK2_US))[(nt * 2 + mt2) * 64 + lane];
  float4 b2q[2];
#pragma unroll
  for (int mt2 = 0; mt2 < 2; ++mt2)
    b2q[mt2] = *(const float4*)(wsf + B2F_F + mt2 * 16 + quad * 4);

#pragma unroll
  for (int i = 0; i < 4; ++i) {
    v4f a2[2];
    a2[0] = (v4f){b2q[0].x, b2q[0].y, b2q[0].z, b2q[0].w};
    a2[1] = (v4f){b2q[1].x, b2q[1].y, b2q[1].z, b2q[1].w};
#pragma unroll
    for (int nt = 0; nt < 4; ++nt) {
      float r0 = fmaxf(acc[i][nt][0], 0.f);
      float r1 = fmaxf(acc[i][nt][1], 0.f);
      float r2 = fmaxf(acc[i][nt][2], 0.f);
      float r3 = fmaxf(acc[i][nt][3], 0.f);
      unsigned int u0 = cvtpk(r0, r1), u1 = cvtpk(r2, r3);
      union { unsigned int q[4]; v8s v; } bu;
      bu.q[0] = u0; bu.q[1] = u1; bu.q[2] = u0; bu.q[3] = u1;
#pragma unroll
      for (int mt2 = 0; mt2 < 2; ++mt2)
        a2[mt2] = __builtin_amdgcn_mfma_f32_16x16x32_bf16(w2f[nt][mt2], bu.v, a2[mt2], 0, 0, 0);
    }
    int pix = pix0_[i] + lc;
    int gy = y0 + (pix >> 5), gx = x0 + (pix & 31);
    ushort_t* dst = h2 + (((b * 256 + gy) * 256 + gx) << 5) + (quad << 2);
#pragma unroll
    for (int mt2 = 0; mt2 < 2; ++mt2) {
      float v0 = fmaxf(a2[mt2][0], 0.f);
      float v1 = fmaxf(a2[mt2][1], 0.f);
      float v2 = fmaxf(a2[mt2][2], 0.f);
      float v3 = fmaxf(a2[mt2][3], 0.f);
      unsigned long long q =
          (unsigned long long)cvtpk(v0, v1) |
          ((unsigned long long)cvtpk(v2, v3) << 32);
      *(unsigned long long*)(dst + mt2 * 16) = q;
    }
  }
}

// ---------------- K3: MFMA conv5x5(32->4) via dx-in-N trick ----------------
// r2-exact body (proven best): grid dim3(8,16,16), Wf[0..31] in registers,
// ks 32..39 streamed from L2, launch_bounds(256,3).
__global__ __launch_bounds__(256, 3) void k_conv3(
    const ushort_t* __restrict__ h2, const ushort_t* __restrict__ wsus,
    const float* __restrict__ wsf, void* __restrict__ out,
    const int* __restrict__ flag) {
  __shared__ __align__(16) ushort_t patch[20 * 1160];  // [y 20][x 36][ic 32] + 8 pad/row
  const int b  = blockIdx.z;
  const int x0 = blockIdx.x * 32, y0 = blockIdx.y * 16;
  const int tid = threadIdx.x;

  for (int e = tid; e < 720; e += 256) {
    int yy = e / 36, xx = e - yy * 36;
    int gy = y0 + yy - 2, gx = x0 + xx - 2;
    ushort_t* dst = patch + yy * 1160 + xx * 32;
    if (gy >= 0 && gy < 256 && gx >= 0 && gx < 256) {
      const ushort_t* src = h2 + (((b * 256 + gy) * 256 + gx) << 5);
#pragma unroll
      for (int c = 0; c < 4; ++c)
        *(float4*)(dst + c * 8) = *(const float4*)(src + c * 8);
    } else {
      float4 z = make_float4(0.f, 0.f, 0.f, 0.f);
#pragma unroll
      for (int c = 0; c < 4; ++c) *(float4*)(dst + c * 8) = z;
    }
  }

  const int lane = tid & 63, wave = tid >> 6;
  const int quad = lane >> 4, lc = lane & 15;

  // preload conv3 weight frags ks 0..31 into registers (32 x v8s = 128 VGPR)
  const v8s* __restrict__ Bp3 = (const v8s*)(wsus + PK3_US);
  v8s Wf[32];
#pragma unroll
  for (int ks = 0; ks < 32; ++ks) Wf[ks] = Bp3[ks * 64 + lane];
  __syncthreads();

  // bias b3 folded into accumulator init
  float b3v = (wsf + B3F_F)[lc & 3];
  v4f acc[2];
  acc[0] = (v4f){b3v, b3v, b3v, b3v};
  acc[1] = (v4f){b3v, b3v, b3v, b3v};

#pragma unroll
  for (int ks = 0; ks < 40; ++ks) {
    int ky = ks >> 3, j = ks & 7;
    int rowoff = (lc + ky) * 1160 + j * 32 + quad * 8;
    v8s Bf = (ks < 32) ? Wf[ks] : Bp3[ks * 64 + lane];
#pragma unroll
    for (int i = 0; i < 2; ++i) {
      int q = wave * 2 + i;
      v8s Af = *(const v8s*)(patch + rowoff + q * 128);
      acc[i] = __builtin_amdgcn_mfma_f32_16x16x32_bf16(Af, Bf, acc[i], 0, 0, 0);
    }
  }

  // epilogue: C/D row=quad*4+r -> y_local, col=lc -> (dx=lc>>2, oc=lc&3)
  const int fl = flag[0];
#pragma unroll
  for (int i = 0; i < 2; ++i) {
    int q = wave * 2 + i;
#pragma unroll
    for (int r = 0; r < 4; ++r) {
      int gy = y0 + (quad << 2) + r;
      int gx = x0 + (q << 2) + (lc >> 2);
      int idx = (((b * 256 + gy) * 256 + gx) << 2) + (lc & 3);
      float vv = acc[i][r];
      if (fl) ((ushort_t*)out)[idx] = f2us(vv);
      else    ((float*)out)[idx] = vv;
    }
  }
}

// ---------------------------------------------------------------------------
extern "C" void kernel_launch(void* const* d_in, const int* in_sizes, int n_in,
                              void* d_out, int out_size, void* d_ws, size_t ws_size,
                              hipStream_t stream) {
  const void* x  = d_in[0];
  const void* w1 = d_in[1];
  const void* b1 = d_in[2];
  const void* w2 = d_in[3];
  const void* b2 = d_in[4];
  const void* w3 = d_in[5];
  const void* b3 = d_in[6];

  ushort_t* wsus = (ushort_t*)d_ws;
  float* wsf = (float*)d_ws;
  int* flag = (int*)((float*)d_ws + FLAG_I);
  ushort_t* h2 = wsus + H2_US;

  k_cvt<<<(CVT_TOTAL + 255) / 256, 256, 0, stream>>>(x, w1, b1, w2, b2, w3, b3,
                                                     wsus, wsf, flag);
  k_conv12<<<dim3(8, 16, 16), 512, 0, stream>>>(x, wsus, wsf, h2, flag);
  k_conv3<<<dim3(8, 16, 16), 256, 0, stream>>>(h2, wsus, wsf, d_out, flag);
}

// Round 8
// 145.514 us; speedup vs baseline: 3.4304x; 1.0184x over previous
//
#include <hip/hip_runtime.h>
#include <hip/hip_bf16.h>

typedef unsigned short ushort_t;
typedef __attribute__((ext_vector_type(8))) short v8s;   // 8 bf16 = 4 VGPR (MFMA A/B)
typedef __attribute__((ext_vector_type(4))) float v4f;   // MFMA C/D

// ---------------------------------------------------------------------------
// ws layout (ushort indices unless noted):
//   pack1 [0, 22528)        conv1 A-frags (weights), dense K: [ks 11][nt 4][lane 64][8]
//   pack2 [22528, 26624)    conv2 A-frags hi|lo-in-j: [nt 4][mt2 2][lane 64][8]
//   pack3 [26624, 47104)    conv3 B-frags (hi only): [ks 40][lane 64][8]
//   floats at us 47104 (float idx 23552):
#define B1F_F   23552      // 64
#define B2F_F   23616      // 32
#define B3F_F   23648      // 4
#define WTAB_F  23652      // 32 (8 phases x 4 taps)
#define FLAG_I  23684      // int (1 = bf16 inputs/outputs, 0 = fp32)
#define PK1_US  0
#define PK2_US  22528
#define PK3_US  26624
#define H2_US   4242560    // bf16 NHWC [16][256][256][32] (32M us = 64 MB)
#define CVT_TOTAL (47104 + 132)
// ---------------------------------------------------------------------------

__device__ __forceinline__ ushort_t f2us(float v) {
  __hip_bfloat16 h = __float2bfloat16(v);
  return *reinterpret_cast<ushort_t*>(&h);
}
__device__ __forceinline__ float us2f(unsigned int u) { return __uint_as_float(u << 16); }

// RNE-pack two finite floats into two bf16 (lo = a, hi = b). Bit-exact RNE.
__device__ __forceinline__ unsigned int bfpair(float a, float b) {
  unsigned int ua = __float_as_uint(a), ub = __float_as_uint(b);
  ua += 0x7fffu + ((ua >> 16) & 1u);
  ub += 0x7fffu + ((ub >> 16) & 1u);
  return (ua >> 16) | (ub & 0xffff0000u);
}

// HW packed f32->bf16 (RNE under default MODE.round) — 1 VALU op vs ~7 for bfpair.
__device__ __forceinline__ unsigned int cvtpk(float a, float b) {
  unsigned int r;
  asm("v_cvt_pk_bf16_f32 %0, %1, %2" : "=v"(r) : "v"(a), "v"(b));
  return r;
}

// direct global -> LDS DMA, 16 B per lane (dest must be linear in lane order)
__device__ __forceinline__ void gload_lds16(const void* g, void* l) {
  __builtin_amdgcn_global_load_lds(
      (const __attribute__((address_space(1))) void*)g,
      (__attribute__((address_space(3))) void*)l, 16, 0, 0);
}

__device__ __forceinline__ float load_in(const void* p, int i, int isbf16) {
  if (isbf16) return us2f(((const unsigned short*)p)[i]);
  return ((const float*)p)[i];
}
__device__ __forceinline__ float4 load_in4(const void* p, int i4, int isbf16) {
  if (isbf16) {
    unsigned long long q = *(const unsigned long long*)((const unsigned short*)p + i4);
    return make_float4(us2f((unsigned int)(q & 0xffff)),
                       us2f((unsigned int)((q >> 16) & 0xffff)),
                       us2f((unsigned int)((q >> 32) & 0xffff)),
                       us2f((unsigned int)((q >> 48) & 0xffff)));
  }
  return *(const float4*)((const float*)p + i4);
}

__device__ __forceinline__ float cubicw(float d) {
  const float Ac = -0.75f;
  d = fabsf(d);
  float d2 = d * d, d3 = d2 * d;
  if (d <= 1.f) return (Ac + 2.f) * d3 - (Ac + 3.f) * d2 + 1.f;
  if (d < 2.f)  return Ac * d3 - 5.f * Ac * d2 + 8.f * Ac * d - 4.f * Ac;
  return 0.f;
}

// ---------------- K_cvt: inline dtype probe + build weight packs -----------
__global__ __launch_bounds__(256) void k_cvt(
    const void* __restrict__ x,
    const void* __restrict__ w1, const void* __restrict__ b1,
    const void* __restrict__ w2, const void* __restrict__ b2,
    const void* __restrict__ w3, const void* __restrict__ b3,
    ushort_t* __restrict__ wsus, float* __restrict__ wsf,
    int* __restrict__ flag) {
  __shared__ int scnt;
  const int tid = threadIdx.x;
  if (tid == 0) scnt = 0;
  __syncthreads();
  {
    const unsigned short* xr = (const unsigned short*)x;
    int c = 0;
    for (int s = tid; s < 512; s += 256) {
      unsigned short h = xr[2 * s];
      int e = (h >> 7) & 0xFF;
      if (e >= 110 && e <= 135) c++;
    }
    if (c) atomicAdd(&scnt, c);
  }
  __syncthreads();
  const int f = (scnt >= 256) ? 1 : 0;
  if (blockIdx.x == 0 && tid == 0) flag[0] = f;

  int i = blockIdx.x * 256 + tid;
  if (i >= CVT_TOTAL) return;
  if (i < 22528) {
    // pack1 dense: k = ks*32+quad*8+j; k<324: tap=k>>2 (ky=tap/9,kx=tap%9), ic=k&3
    int j  = i & 7;
    int l  = (i >> 3) & 63;
    int nt = (i >> 9) & 3;
    int ks = i >> 11;
    int k  = ks * 32 + ((l >> 4) & 3) * 8 + j;
    int oc = nt * 16 + (l & 15);
    float v = 0.f;
    if (k < 324) {
      int tap = k >> 2, ic = k & 3;
      int ky = tap / 9, kx = tap - ky * 9;
      v = load_in(w1, ((oc * 4 + ic) * 9 + ky) * 9 + kx, f);
    }
    wsus[PK1_US + i] = f2us(v);
    return;
  }
  if (i < 26624) {
    // pack2: [nt][mt2][lane][8]; j<4 = hi(w2), j>=4 = lo residual
    int t = i - 22528;
    int j   = t & 7;
    int l   = (t >> 3) & 63;
    int mt2 = (t >> 9) & 1;
    int nt  = (t >> 10) & 3;
    int oc1 = nt * 16 + ((l >> 4) & 3) * 4 + (j & 3);
    int oc2 = mt2 * 16 + (l & 15);
    float w = load_in(w2, oc2 * 64 + oc1, f);
    float hi = us2f(f2us(w));
    wsus[PK2_US + t] = (j < 4) ? f2us(w) : f2us(w - hi);
    return;
  }
  if (i < 47104) {
    // pack3 (hi only): [ks 40][lane][8]; k=ky*256+jj*32+ic; n=dx*4+oc
    int t = i - 26624;
    int j8 = t & 7;
    int l  = (t >> 3) & 63;
    int ks = t >> 9;
    int k  = ks * 32 + ((l >> 4) & 3) * 8 + j8;
    int n  = l & 15;
    int ky = k >> 8, jj = (k >> 5) & 7, ic = k & 31;
    int dx = n >> 2, oc = n & 3;
    int kx = jj - dx;
    float w = 0.f;
    if (kx >= 0 && kx <= 4)
      w = load_in(w3, ((oc * 32 + ic) * 5 + ky) * 5 + kx, f);
    wsus[PK3_US + t] = f2us(w);
    return;
  }
  int t = i - 47104;
  if (t < 64) { wsf[B1F_F + t] = load_in(b1, t, f); return; }
  if (t < 96) { wsf[B2F_F + (t - 64)] = load_in(b2, t - 64, f); return; }
  if (t < 100) { wsf[B3F_F + (t - 96)] = load_in(b3, t - 96, f); return; }
  if (t < 132) {
    int p = (t - 100) >> 2, a = (t - 100) & 3;
    float frac = (p + 0.5f) * 0.125f - 0.5f;
    float fl = floorf(frac);
    float tt = frac - fl;
    wsf[WTAB_F + (t - 100)] = cubicw(tt - (float)(a - 1));
  }
}

// ---------------- K2: fused bicubic-x8 + conv9x9(4->64)+ReLU + conv1x1 ----
// r2-proven MFMA structure; upscale fused into staging via TWO-PHASE LDS
// x-filter: all 24 patch rows share ONE block-uniform by0 (= y0/8 - 1 for
// every gy0 in [y0-4, y0+3] -- proof in notes), so the 6 x-filtered source
// rows are computed ONCE (240 tasks, phase 1 -> xfL f32) instead of 8x
// redundantly per thread (r7).  Phase 2 y-combines 960 outputs from xfL
// with the identical fmaf chain + bfpair -> bit-identical patch bits.
// Global staging loads drop 7680 -> 960 per block; staging VALU ~halves.
// NOTE (r4): acc[4][4] fits the (512,4) 128-reg budget; acc[8][4] spills.
// NOTE (r5): no XCD swizzles based on assumed dispatch order.
__global__ __launch_bounds__(512, 4) void k_conv12(
    const void* __restrict__ x, const ushort_t* __restrict__ wsus,
    const float* __restrict__ wsf, ushort_t* __restrict__ h2,
    const int* __restrict__ flag) {
  __shared__ __align__(16) ushort_t patchA[24 * 40 * 4];  // 7680 B
  __shared__ __align__(16) ushort_t pack1L[22528];        // 45056 B
  __shared__ __align__(16) float xfL[6 * 40 * 4];         // 3840 B (x-filtered rows)
  const int b  = blockIdx.z;
  const int x0 = blockIdx.x * 32, y0 = blockIdx.y * 16;
  const int tid = threadIdx.x;
  const int f = flag[0];

  // stage pack1 -> LDS via direct DMA (2816 x 16B; dest linear in lane order)
  {
    const ushort_t* src = wsus + PK1_US;
#pragma unroll
    for (int i = 0; i < 6; ++i) {
      int e = tid + i * 512;
      if (e < 2816)                              // wave-uniform guard
        gload_lds16(src + e * 8, pack1L + e * 8);
    }
  }

  const float* wt = wsf + WTAB_F;
  // phase 1: x-filter the 6 block-uniform source rows once (f32, exact)
  {
    const int by0 = (y0 >> 3) - 1;               // uniform across the block
    if (tid < 240) {
      int j = tid / 40, xx = tid - j * 40;
      int gx = x0 + xx - 4;
      int pxv = gx & 7;
      float4 wx = *(const float4*)(wt + pxv * 4);
      int bx = (gx >> 3) + ((pxv >= 4) ? 0 : -1);
      int ix0 = min(max(bx - 1, 0), 31), ix1 = min(max(bx, 0), 31);
      int ix2 = min(max(bx + 1, 0), 31), ix3 = min(max(bx + 2, 0), 31);
      int iy = min(max(by0 - 1 + j, 0), 31);
      int rowb = (b * 32 + iy) * 32;
      float4 p0 = load_in4(x, (rowb + ix0) * 4, f);
      float4 p1 = load_in4(x, (rowb + ix1) * 4, f);
      float4 p2 = load_in4(x, (rowb + ix2) * 4, f);
      float4 p3 = load_in4(x, (rowb + ix3) * 4, f);
      float4 fr;
      fr.x = wx.x * p0.x + wx.y * p1.x + wx.z * p2.x + wx.w * p3.x;
      fr.y = wx.x * p0.y + wx.y * p1.y + wx.z * p2.y + wx.w * p3.y;
      fr.z = wx.x * p0.z + wx.y * p1.z + wx.z * p2.z + wx.w * p3.z;
      fr.w = wx.x * p0.w + wx.y * p1.w + wx.z * p2.w + wx.w * p3.w;
      *(float4*)(xfL + (j * 40 + xx) * 4) = fr;
    }
  }
  __syncthreads();
  // phase 2: y-combine 24x40 outputs from xfL (identical fmaf chain + pack)
  {
#pragma unroll
    for (int rep = 0; rep < 2; ++rep) {
      int e = tid + rep * 512;                   // need 960
      if (e < 960) {
        int r = e / 40, xx = e - r * 40;         // patch row r = yy + 8*o
        int gy = y0 + r - 4, gx = x0 + xx - 4;
        unsigned long long q = 0ull;
        if (gx >= 0 && gx < 256 && gy >= 0 && gy < 256) {
          int o = r >> 3;
          int pyv = gy & 7;
          float4 wy = *(const float4*)(wt + pyv * 4);
          float wya[4] = {wy.x, wy.y, wy.z, wy.w};
          float ax = 0.f, ay = 0.f, az = 0.f, aw = 0.f;
#pragma unroll
          for (int a = 0; a < 4; a++) {
            float4 fr = *(const float4*)(xfL + ((o + a) * 40 + xx) * 4);
            ax = fmaf(wya[a], fr.x, ax); ay = fmaf(wya[a], fr.y, ay);
            az = fmaf(wya[a], fr.z, az); aw = fmaf(wya[a], fr.w, aw);
          }
          q = (unsigned long long)bfpair(ax, ay) |
              ((unsigned long long)bfpair(az, aw) << 32);
        }
        *(unsigned long long*)(patchA + e * 4) = q;
      }
    }
  }
  __syncthreads();

  const int lane = tid & 63, wave = tid >> 6;
  const int quad = lane >> 4, lc = lane & 15;
  int base_m[4], pix0_[4];
#pragma unroll
  for (int i = 0; i < 4; ++i) {
    int mt = wave * 4 + i;                   // 0..31
    int py = mt >> 1, pxh = (mt & 1) << 4;   // py 0..15, pxh 0/16
    base_m[i] = (py * 40 + pxh + lc) << 2;   // ushort idx of (py, pxh+lc, ic0)
    pix0_[i] = py * 32 + pxh;
  }

  // bias b1 -> accumulator init (C-in of the first MFMA)
  float4 b1q[4];
#pragma unroll
  for (int nt = 0; nt < 4; ++nt)
    b1q[nt] = *(const float4*)(wsf + B1F_F + nt * 16 + quad * 4);
  v4f acc[4][4];
#pragma unroll
  for (int i = 0; i < 4; ++i)
#pragma unroll
    for (int nt = 0; nt < 4; ++nt)
      acc[i][nt] = (v4f){b1q[nt].x, b1q[nt].y, b1q[nt].z, b1q[nt].w};

  const v8s* __restrict__ Ap1 = (const v8s*)pack1L;
#pragma unroll
  for (int ks = 0; ks < 11; ++ks) {
    v8s Af[4];
#pragma unroll
    for (int nt = 0; nt < 4; ++nt) Af[nt] = Ap1[(ks * 4 + nt) * 64 + lane];
    int tap0 = ks * 8 + quad * 2;
    int tap1 = min(tap0 + 1, 80);
    tap0 = min(tap0, 80);
    int ky0 = tap0 / 9, kx0 = tap0 - ky0 * 9;
    int ky1 = tap1 / 9, kx1 = tap1 - ky1 * 9;
    int off0 = (ky0 * 40 + kx0) << 2;
    int off1 = (ky1 * 40 + kx1) << 2;
#pragma unroll
    for (int i = 0; i < 4; ++i) {
      union { unsigned long long q[2]; v8s v; } u;
      u.q[0] = *(const unsigned long long*)(patchA + base_m[i] + off0);
      u.q[1] = *(const unsigned long long*)(patchA + base_m[i] + off1);
#pragma unroll
      for (int nt = 0; nt < 4; ++nt)
        acc[i][nt] = __builtin_amdgcn_mfma_f32_16x16x32_bf16(Af[nt], u.v, acc[i][nt], 0, 0, 0);
    }
  }

  // epilogue: ReLU, pack -> conv2 MFMA (b2 folded into C-init) -> ReLU, store
  v8s w2f[4][2];
#pragma unroll
  for (int nt = 0; nt < 4; ++nt)
#pragma unroll
    for (int mt2 = 0; mt2 < 2; ++mt2)
      w2f[nt][mt2] = ((const v8s*)(wsus + PK2_US))[(nt * 2 + mt2) * 64 + lane];
  float4 b2q[2];
#pragma unroll
  for (int mt2 = 0; mt2 < 2; ++mt2)
    b2q[mt2] = *(const float4*)(wsf + B2F_F + mt2 * 16 + quad * 4);

#pragma unroll
  for (int i = 0; i < 4; ++i) {
    v4f a2[2];
    a2[0] = (v4f){b2q[0].x, b2q[0].y, b2q[0].z, b2q[0].w};
    a2[1] = (v4f){b2q[1].x, b2q[1].y, b2q[1].z, b2q[1].w};
#pragma unroll
    for (int nt = 0; nt < 4; ++nt) {
      float r0 = fmaxf(acc[i][nt][0], 0.f);
      float r1 = fmaxf(acc[i][nt][1], 0.f);
      float r2 = fmaxf(acc[i][nt][2], 0.f);
      float r3 = fmaxf(acc[i][nt][3], 0.f);
      unsigned int u0 = cvtpk(r0, r1), u1 = cvtpk(r2, r3);
      union { unsigned int q[4]; v8s v; } bu;
      bu.q[0] = u0; bu.q[1] = u1; bu.q[2] = u0; bu.q[3] = u1;
#pragma unroll
      for (int mt2 = 0; mt2 < 2; ++mt2)
        a2[mt2] = __builtin_amdgcn_mfma_f32_16x16x32_bf16(w2f[nt][mt2], bu.v, a2[mt2], 0, 0, 0);
    }
    int pix = pix0_[i] + lc;
    int gy = y0 + (pix >> 5), gx = x0 + (pix & 31);
    ushort_t* dst = h2 + (((b * 256 + gy) * 256 + gx) << 5) + (quad << 2);
#pragma unroll
    for (int mt2 = 0; mt2 < 2; ++mt2) {
      float v0 = fmaxf(a2[mt2][0], 0.f);
      float v1 = fmaxf(a2[mt2][1], 0.f);
      float v2 = fmaxf(a2[mt2][2], 0.f);
      float v3 = fmaxf(a2[mt2][3], 0.f);
      unsigned long long q =
          (unsigned long long)cvtpk(v0, v1) |
          ((unsigned long long)cvtpk(v2, v3) << 32);
      *(unsigned long long*)(dst + mt2 * 16) = q;
    }
  }
}

// ---------------- K3: MFMA conv5x5(32->4) via dx-in-N trick ----------------
// r2-exact body (proven best): grid dim3(8,16,16), Wf[0..31] in registers,
// ks 32..39 streamed from L2, launch_bounds(256,3).
__global__ __launch_bounds__(256, 3) void k_conv3(
    const ushort_t* __restrict__ h2, const ushort_t* __restrict__ wsus,
    const float* __restrict__ wsf, void* __restrict__ out,
    const int* __restrict__ flag) {
  __shared__ __align__(16) ushort_t patch[20 * 1160];  // [y 20][x 36][ic 32] + 8 pad/row
  const int b  = blockIdx.z;
  const int x0 = blockIdx.x * 32, y0 = blockIdx.y * 16;
  const int tid = threadIdx.x;

  for (int e = tid; e < 720; e += 256) {
    int yy = e / 36, xx = e - yy * 36;
    int gy = y0 + yy - 2, gx = x0 + xx - 2;
    ushort_t* dst = patch + yy * 1160 + xx * 32;
    if (gy >= 0 && gy < 256 && gx >= 0 && gx < 256) {
      const ushort_t* src = h2 + (((b * 256 + gy) * 256 + gx) << 5);
#pragma unroll
      for (int c = 0; c < 4; ++c)
        *(float4*)(dst + c * 8) = *(const float4*)(src + c * 8);
    } else {
      float4 z = make_float4(0.f, 0.f, 0.f, 0.f);
#pragma unroll
      for (int c = 0; c < 4; ++c) *(float4*)(dst + c * 8) = z;
    }
  }

  const int lane = tid & 63, wave = tid >> 6;
  const int quad = lane >> 4, lc = lane & 15;

  // preload conv3 weight frags ks 0..31 into registers (32 x v8s = 128 VGPR)
  const v8s* __restrict__ Bp3 = (const v8s*)(wsus + PK3_US);
  v8s Wf[32];
#pragma unroll
  for (int ks = 0; ks < 32; ++ks) Wf[ks] = Bp3[ks * 64 + lane];
  __syncthreads();

  // bias b3 folded into accumulator init
  float b3v = (wsf + B3F_F)[lc & 3];
  v4f acc[2];
  acc[0] = (v4f){b3v, b3v, b3v, b3v};
  acc[1] = (v4f){b3v, b3v, b3v, b3v};

#pragma unroll
  for (int ks = 0; ks < 40; ++ks) {
    int ky = ks >> 3, j = ks & 7;
    int rowoff = (lc + ky) * 1160 + j * 32 + quad * 8;
    v8s Bf = (ks < 32) ? Wf[ks] : Bp3[ks * 64 + lane];
#pragma unroll
    for (int i = 0; i < 2; ++i) {
      int q = wave * 2 + i;
      v8s Af = *(const v8s*)(patch + rowoff + q * 128);
      acc[i] = __builtin_amdgcn_mfma_f32_16x16x32_bf16(Af, Bf, acc[i], 0, 0, 0);
    }
  }

  // epilogue: C/D row=quad*4+r -> y_local, col=lc -> (dx=lc>>2, oc=lc&3)
  const int fl = flag[0];
#pragma unroll
  for (int i = 0; i < 2; ++i) {
    int q = wave * 2 + i;
#pragma unroll
    for (int r = 0; r < 4; ++r) {
      int gy = y0 + (quad << 2) + r;
      int gx = x0 + (q << 2) + (lc >> 2);
      int idx = (((b * 256 + gy) * 256 + gx) << 2) + (lc & 3);
      float vv = acc[i][r];
      if (fl) ((ushort_t*)out)[idx] = f2us(vv);
      else    ((float*)out)[idx] = vv;
    }
  }
}

// ---------------------------------------------------------------------------
extern "C" void kernel_launch(void* const* d_in, const int* in_sizes, int n_in,
                              void* d_out, int out_size, void* d_ws, size_t ws_size,
                              hipStream_t stream) {
  const void* x  = d_in[0];
  const void* w1 = d_in[1];
  const void* b1 = d_in[2];
  const void* w2 = d_in[3];
  const void* b2 = d_in[4];
  const void* w3 = d_in[5];
  const void* b3 = d_in[6];

  ushort_t* wsus = (ushort_t*)d_ws;
  float* wsf = (float*)d_ws;
  int* flag = (int*)((float*)d_ws + FLAG_I);
  ushort_t* h2 = wsus + H2_US;

  k_cvt<<<(CVT_TOTAL + 255) / 256, 256, 0, stream>>>(x, w1, b1, w2, b2, w3, b3,
                                                     wsus, wsf, flag);
  k_conv12<<<dim3(8, 16, 16), 512, 0, stream>>>(x, wsus, wsf, h2, flag);
  k_conv3<<<dim3(8, 16, 16), 256, 0, stream>>>(h2, wsus, wsf, d_out, flag);
}